// Round 1
// 277.900 us; speedup vs baseline: 1.0448x; 1.0448x over previous
//
#include <hip/hip_runtime.h>
#include <hip/hip_bf16.h>

#define NN 20000
#define IN 128
#define HH 2
#define DD 32
#define HD 64
#define KK 3
#define RR 5
#define EE 320000
#define NEG 0.2f

#define PADK 136
#define NB 313     // buckets per relation (64 dsts each)
#define NBLK 64    // partition blocks per relation
#define CHUNK 5000 // EE / NBLK
#define CAP 2048   // max edges per bucket (mean 1024, sd ~32)
#define RPS 20004  // rowp row stride (NN+4, 16B-aligned rows; sentinel at [NN])

typedef short v8s __attribute__((ext_vector_type(8)));
typedef float v4f __attribute__((ext_vector_type(4)));
typedef _Float16 hf8 __attribute__((ext_vector_type(8)));

__device__ __forceinline__ ushort f2b(float f) {
    unsigned u = __float_as_uint(f);
    unsigned r = (u + 0x7fff + ((u >> 16) & 1)) >> 16;   // RNE
    return (ushort)r;
}
__device__ __forceinline__ ushort f2h(float f) {
    _Float16 h = (_Float16)f;
    return __builtin_bit_cast(ushort, h);
}
__device__ __forceinline__ float h2f(ushort u) {
    _Float16 h = __builtin_bit_cast(_Float16, u);
    return (float)h;
}
__device__ __forceinline__ float2 up2(unsigned u) {
    return make_float2(h2f((ushort)(u & 0xFFFF)), h2f((ushort)(u >> 16)));
}

// ---------------------------------------------------------------------------
// K0: weights -> wb bf16, transposed+fused: wb[r][col][k], col<64=fc else res
// (h conversion now fused into proj_mfma staging)
// ---------------------------------------------------------------------------
__global__ __launch_bounds__(256) void cvt_kernel(
    const float* __restrict__ fcw, const float* __restrict__ resw,
    ushort* __restrict__ wb)
{
    int j = blockIdx.x * 256 + threadIdx.x;
    if (j >= RR * 128 * IN) return;
    int k = j & 127;
    int c = (j >> 7) & 127;
    int r = j >> 14;
    float v = (c < HD) ? fcw[(r * IN + k) * HD + c] : resw[(r * IN + k) * HD + (c - HD)];
    wb[j] = f2b(v);
}

// ---------------------------------------------------------------------------
// K1: projection via bf16 MFMA; reads fp32 h directly (cvt in staging);
// emits fp16 table t0 (x) and fp16 res.
// ---------------------------------------------------------------------------
__global__ __launch_bounds__(256) void proj_mfma(
    const float* __restrict__ h, const ushort* __restrict__ wb,
    ushort* __restrict__ t0, ushort* __restrict__ resh)
{
    __shared__ ushort As[64 * PADK];
    __shared__ ushort Bs[128 * PADK];
    int bx = blockIdx.x;
    int r = bx / 313;
    int tile = bx - r * 313;
    int n0 = tile * 64;
    int tid = threadIdx.x;

    // stage A: 64 rows x 128 k, fp32 -> bf16. 2048 float4 chunks / 256 = 8 ea.
    #pragma unroll
    for (int i = 0; i < 8; i++) {
        int c = tid + 256 * i;
        int row = c >> 5;            // 32 float4 per row
        int off = (c & 31) * 4;
        int gn = n0 + row;
        float4 v = make_float4(0.f, 0.f, 0.f, 0.f);
        if (gn < NN) v = *(const float4*)&h[(size_t)gn * IN + off];
        *(ushort4*)&As[row * PADK + off] =
            make_ushort4(f2b(v.x), f2b(v.y), f2b(v.z), f2b(v.w));
    }
    const ushort* wr = wb + (size_t)r * 128 * IN;
    #pragma unroll
    for (int i = 0; i < 8; i++) {
        int c = tid + 256 * i;
        int row = c >> 4;
        int off = (c & 15) * 8;
        *(uint4*)&Bs[row * PADK + off] = *(const uint4*)&wr[row * IN + off];
    }
    __syncthreads();

    int w = tid >> 6, lane = tid & 63;
    int lm = lane & 15, lq = lane >> 4;

    v4f acc[4][2];
    #pragma unroll
    for (int mt = 0; mt < 4; mt++)
        #pragma unroll
        for (int nt = 0; nt < 2; nt++) acc[mt][nt] = (v4f){0.f, 0.f, 0.f, 0.f};

    const ushort* Ab = &As[lm * PADK + lq * 8];
    const ushort* Bb = &Bs[(w * 32 + lm) * PADK + lq * 8];

    #pragma unroll
    for (int ks = 0; ks < 4; ks++) {
        v8s a[4], b[2];
        #pragma unroll
        for (int mt = 0; mt < 4; mt++) a[mt] = *(const v8s*)(Ab + mt * 16 * PADK + ks * 32);
        #pragma unroll
        for (int nt = 0; nt < 2; nt++) b[nt] = *(const v8s*)(Bb + nt * 16 * PADK + ks * 32);
        #pragma unroll
        for (int mt = 0; mt < 4; mt++)
            #pragma unroll
            for (int nt = 0; nt < 2; nt++)
                acc[mt][nt] = __builtin_amdgcn_mfma_f32_16x16x32_bf16(a[mt], b[nt], acc[mt][nt], 0, 0, 0);
    }

    int colbase = w * 32 + lm;
    #pragma unroll
    for (int mt = 0; mt < 4; mt++) {
        #pragma unroll
        for (int nt = 0; nt < 2; nt++) {
            int col = colbase + nt * 16;
            #pragma unroll
            for (int p = 0; p < 4; p++) {
                int node = n0 + mt * 16 + lq * 4 + p;
                if (node < NN) {
                    float v = acc[mt][nt][p];
                    if (col < HD) {
                        t0[((size_t)r * NN + node) * HD + col] = f2h(v);
                    } else {
                        resh[((size_t)r * NN + node) * HD + (col - HD)] = f2h(v);
                    }
                }
            }
        }
    }
}

// ---------------------------------------------------------------------------
// K1b: per-node attention scalars el/er from fp16 t0
// ---------------------------------------------------------------------------
__global__ __launch_bounds__(256) void attn_node_kernel(
    const ushort* __restrict__ t0, const float* __restrict__ attn_l,
    const float* __restrict__ attn_r, float* __restrict__ el,
    float* __restrict__ er)
{
    int idx = blockIdx.x * 256 + threadIdx.x;
    if (idx >= RR * NN * HH) return;
    int h_ = idx & 1;
    int n = (idx >> 1) % NN;
    int r = idx / (NN * HH);
    const ushort* x = t0 + ((size_t)r * NN + n) * HD + h_ * DD;
    const float* al = attn_l + (r * HH + h_) * DD;
    const float* ar = attn_r + (r * HH + h_) * DD;
    uint4 p0 = *(const uint4*)(x);
    uint4 p1 = *(const uint4*)(x + 8);
    uint4 p2 = *(const uint4*)(x + 16);
    uint4 p3 = *(const uint4*)(x + 24);
    unsigned P[8] = {p0.x, p0.y, p0.z, p0.w, p1.x, p1.y, p1.z, p1.w};
    unsigned Q[8] = {p2.x, p2.y, p2.z, p2.w, p3.x, p3.y, p3.z, p3.w};
    float sl = 0.f, sr = 0.f;
    #pragma unroll
    for (int j = 0; j < 8; j++) {
        float2 v = up2(P[j]);
        sl += v.x * al[2 * j] + v.y * al[2 * j + 1];
        sr += v.x * ar[2 * j] + v.y * ar[2 * j + 1];
    }
    #pragma unroll
    for (int j = 0; j < 8; j++) {
        float2 v = up2(Q[j]);
        sl += v.x * al[16 + 2 * j] + v.y * al[16 + 2 * j + 1];
        sr += v.x * ar[16 + 2 * j] + v.y * ar[16 + 2 * j + 1];
    }
    el[idx] = sl;
    er[idx] = sr;
}

// ---------------------------------------------------------------------------
// A1: per-(relation, block) histogram of 313 buckets over a 5000-edge chunk.
// ---------------------------------------------------------------------------
__global__ __launch_bounds__(256) void bhist_kernel(
    const int* __restrict__ dst, int* __restrict__ blkHist)
{
    __shared__ int hh[NB];
    int r = blockIdx.x >> 6;
    int blk = blockIdx.x & 63;
    int tid = threadIdx.x;
    for (int i = tid; i < NB; i += 256) hh[i] = 0;
    __syncthreads();
    const int* D = dst + (size_t)r * EE + blk * CHUNK;
    for (int i = tid; i < CHUNK; i += 256)
        atomicAdd(&hh[D[i] >> 6], 1);
    __syncthreads();
    for (int i = tid; i < NB; i += 256)
        blkHist[((size_t)(r * NB + i)) * NBLK + blk] = hh[i];
}

// ---------------------------------------------------------------------------
// A2: per-relation exclusive scan over (bkt-major, blk-minor) matrix.
// ---------------------------------------------------------------------------
__global__ __launch_bounds__(256) void mscan_kernel(
    int* __restrict__ blkHist, int* __restrict__ bbase)
{
    __shared__ int wsum[4];
    __shared__ int carry;
    int r = blockIdx.x;
    int tid = threadIdx.x;
    int lane = tid & 63, w = tid >> 6;
    if (tid == 0) carry = 0;
    __syncthreads();
    int4* B4 = (int4*)(blkHist + (size_t)r * NB * NBLK);
    const int M4 = NB * NBLK / 4;   // 5008
    for (int base = 0; base < M4; base += 256) {
        int i4 = base + tid;
        int4 v = (i4 < M4) ? B4[i4] : make_int4(0, 0, 0, 0);
        int s = v.x + v.y + v.z + v.w;
        int x = s;
        #pragma unroll
        for (int off = 1; off < 64; off <<= 1) {
            int t = __shfl_up(x, off, 64);
            if (lane >= off) x += t;
        }
        if (lane == 63) wsum[w] = x;
        __syncthreads();
        int add = carry;
        for (int j = 0; j < w; j++) add += wsum[j];
        int px = add + x - s;
        if (i4 < M4) {
            int p0 = px, p1 = px + v.x, p2 = p1 + v.y, p3 = p2 + v.z;
            B4[i4] = make_int4(p0, p1, p2, p3);
            int e0 = i4 * 4;
            int pr[4] = {p0, p1, p2, p3};
            #pragma unroll
            for (int k = 0; k < 4; k++) {
                int e = e0 + k;
                if ((e & (NBLK - 1)) == 0) bbase[r * (NB + 1) + (e >> 6)] = pr[k];
            }
        }
        __syncthreads();
        if (tid == 255) carry += wsum[0] + wsum[1] + wsum[2] + wsum[3];
        __syncthreads();
    }
    if (tid == 0) bbase[r * (NB + 1) + NB] = EE;
}

// ---------------------------------------------------------------------------
// A3: partition scatter, LDS cursors only, exclusive global slot ranges.
// ---------------------------------------------------------------------------
__global__ __launch_bounds__(256) void bscatter_kernel(
    const int* __restrict__ src, const int* __restrict__ dst,
    const int* __restrict__ blkHist, unsigned* __restrict__ bucketRec)
{
    __shared__ int cur[NB];
    int r = blockIdx.x >> 6;
    int blk = blockIdx.x & 63;
    int tid = threadIdx.x;
    for (int i = tid; i < NB; i += 256)
        cur[i] = blkHist[((size_t)(r * NB + i)) * NBLK + blk];
    __syncthreads();
    const int* S = src + (size_t)r * EE + blk * CHUNK;
    const int* D = dst + (size_t)r * EE + blk * CHUNK;
    unsigned* BR = bucketRec + (size_t)r * EE;
    for (int i = tid; i < CHUNK; i += 256) {
        int s = S[i], d = D[i];
        int pos = atomicAdd(&cur[d >> 6], 1);
        BR[pos] = (unsigned)s | ((unsigned)(d & 63) << 15);
    }
}

// ---------------------------------------------------------------------------
// B: per-bucket LDS counting sort + exact per-dst softmax -> csrE records
// {src | dstLow<<15, half2(w0,w1)} + rowp (stride RPS), sequential writes.
// ---------------------------------------------------------------------------
__global__ __launch_bounds__(256) void bsort_alpha_kernel(
    const unsigned* __restrict__ bucketRec, const int* __restrict__ bbase,
    const float* __restrict__ el, const float* __restrict__ er,
    uint2* __restrict__ csrE, int* __restrict__ rowp)
{
    __shared__ int cnt64s[64];
    __shared__ int segS[65];
    __shared__ int cur[64];
    __shared__ float2 erL[64];
    __shared__ float2 mx2[64];
    __shared__ float2 inv2[64];
    __shared__ unsigned sSD[CAP];
    __shared__ float2 sL[CAP];

    int bk = blockIdx.x;
    int r = bk / NB;
    int bkt = bk - r * NB;
    int tid = threadIdx.x;
    int base = bbase[r * (NB + 1) + bkt];
    int cnt = bbase[r * (NB + 1) + bkt + 1] - base;
    if (cnt > CAP) cnt = CAP;

    if (tid < 64) {
        cnt64s[tid] = 0;
        int gn = bkt * 64 + tid;
        erL[tid] = (gn < NN) ? ((const float2*)er)[(size_t)r * NN + gn]
                             : make_float2(0.f, 0.f);
    }
    __syncthreads();
    const unsigned* BR = bucketRec + (size_t)r * EE + base;
    for (int i = tid; i < cnt; i += 256)
        atomicAdd(&cnt64s[(BR[i] >> 15) & 63], 1);
    __syncthreads();
    if (tid < 64) {
        int v = cnt64s[tid];
        int x = v;
        #pragma unroll
        for (int off = 1; off < 64; off <<= 1) {
            int tt = __shfl_up(x, off, 64);
            if (tid >= off) x += tt;
        }
        segS[tid] = x - v;
        cur[tid] = x - v;
        if (tid == 63) segS[64] = x;
    }
    __syncthreads();
    const float2* el2 = (const float2*)el + (size_t)r * NN;
    for (int i = tid; i < cnt; i += 256) {
        unsigned rec = BR[i];
        int s = rec & 0x7FFF;
        int d = (rec >> 15) & 63;
        float2 a = el2[s];
        float2 b = erL[d];
        float l0 = a.x + b.x; l0 = l0 > 0.f ? l0 : NEG * l0;
        float l1 = a.y + b.y; l1 = l1 > 0.f ? l1 : NEG * l1;
        int pos = atomicAdd(&cur[d], 1);
        sSD[pos] = rec;
        sL[pos] = make_float2(l0, l1);
    }
    __syncthreads();
    if (tid < 64) {
        int b0 = segS[tid], e0 = segS[tid + 1];
        float m0 = -1e30f, m1 = -1e30f;
        for (int i = b0; i < e0; i++) {
            float2 l = sL[i];
            m0 = fmaxf(m0, l.x); m1 = fmaxf(m1, l.y);
        }
        float s0 = 0.f, s1 = 0.f;
        for (int i = b0; i < e0; i++) {
            float2 l = sL[i];
            s0 += __expf(l.x - m0); s1 += __expf(l.y - m1);
        }
        mx2[tid] = make_float2(m0, m1);
        inv2[tid] = make_float2(1.f / fmaxf(s0, 1e-9f), 1.f / fmaxf(s1, 1e-9f));
        int gn = bkt * 64 + tid;
        if (gn < NN) rowp[r * RPS + gn] = base + segS[tid];
    }
    if (bkt == 0 && tid == 64) rowp[r * RPS + NN] = EE;
    __syncthreads();
    uint2* E = csrE + (size_t)r * EE + base;
    for (int i = tid; i < cnt; i += 256) {
        unsigned rec = sSD[i];
        int d = (rec >> 15) & 63;
        float2 l = sL[i];
        float w0 = __expf(l.x - mx2[d].x) * inv2[d].x;
        float w1 = __expf(l.y - mx2[d].y) * inv2[d].y;
        E[i] = make_uint2(rec, (unsigned)f2h(w0) | ((unsigned)f2h(w1) << 16));
    }
}

// ---------------------------------------------------------------------------
// K6: diffusion hop, PULL wide-gather v4: 8 dsts/wave, 8 feats/lane (16 B),
// each dst segment split into TWO interleaved streams (front/back half) ->
// 4 independent VMEM per iteration covering 16 edge-slots.
// v4 changes:
//  - XCD-aware bijective block swizzle (m204): each XCD's L2 sees <=2
//    relation feature tables (<=5.1 MB) instead of all 5 (12.8 MB) ->
//    gathers become L2 hits; hop k's writes stay on the XCD that reads
//    them at hop k+1 (same swizzle every launch).
//  - inner loop consumes fp16 via v_fma_mix (acc += w * (float)h16),
//    removing the shift/mask/cvt unpack chain; fp32 accumulate unchanged.
// ---------------------------------------------------------------------------
__global__ __launch_bounds__(256) void hop_kernel(
    const ushort* __restrict__ tin, ushort* __restrict__ tout,
    const uint2* __restrict__ csrE, const int* __restrict__ rowp)
{
    // bijective XCD swizzle over 8 XCDs (grid = 3125 blocks, 3125 % 8 = 5)
    int nb = gridDim.x;
    int q = nb >> 3, rmd = nb & 7;
    int xcd = blockIdx.x & 7, pos = blockIdx.x >> 3;
    int bid = (xcd < rmd ? xcd * (q + 1) : rmd * (q + 1) + (xcd - rmd) * q) + pos;

    int w = (bid * 256 + (int)threadIdx.x) >> 6;
    if (w >= RR * (NN / 8)) return;
    int lane = threadIdx.x & 63;
    int g = lane >> 3;                 // dst group 0..7
    int f = (lane & 7) * 8;            // feature base 0..56
    int sh = ((lane >> 2) & 1) * 16;   // head select: f>=32 <=> bit2 of lane
    int r = w / (NN / 8);
    int n0 = (w - r * (NN / 8)) * 8;

    const int* rp = rowp + r * RPS + n0 + g;
    int bg = rp[0];
    int eg = rp[1];
    int len = eg - bg;
    int cl = (len + 1) >> 1;           // stream A length (ceil half)
    int b2 = bg + cl;                  // stream B start

    int m = cl;
    m = max(m, __shfl_xor(m, 8, 64));
    m = max(m, __shfl_xor(m, 16, 64));
    m = max(m, __shfl_xor(m, 32, 64));

    int lastA = bg + cl - 1;
    lastA = lastA > bg ? lastA : bg;
    lastA = lastA < (EE - 1) ? lastA : (EE - 1);
    int lastB = eg - 1;
    lastB = lastB > b2 ? lastB : b2;
    lastB = lastB < (EE - 1) ? lastB : (EE - 1);

    const ushort* T = tin + (size_t)r * NN * HD;
    const uint2* E = csrE + (size_t)r * EE;

    float accA[8] = {0.f, 0.f, 0.f, 0.f, 0.f, 0.f, 0.f, 0.f};
    float accB[8] = {0.f, 0.f, 0.f, 0.f, 0.f, 0.f, 0.f, 0.f};
    #pragma unroll 4
    for (int j = 0; j < m; j++) {
        int ia = bg + j;
        int iac = ia < lastA ? ia : lastA;
        int ib = b2 + j;
        int ibc = ib < lastB ? ib : lastB;
        uint2 ra = E[iac];
        uint2 rb = E[ibc];
        float wa = (j < cl) ? h2f((ushort)(ra.y >> sh)) : 0.f;
        float wb = (ib < eg) ? h2f((ushort)(rb.y >> sh)) : 0.f;
        hf8 va = *(const hf8*)&T[(size_t)(ra.x & 0x7FFF) * HD + f];
        hf8 vb = *(const hf8*)&T[(size_t)(rb.x & 0x7FFF) * HD + f];
        #pragma unroll
        for (int k2 = 0; k2 < 8; k2++) {
            accA[k2] += wa * (float)va[k2];
            accB[k2] += wb * (float)vb[k2];
        }
    }
    ushort o[8];
    #pragma unroll
    for (int k = 0; k < 8; k++) o[k] = f2h(accA[k] + accB[k]);
    *(uint4*)&tout[((size_t)r * NN + n0 + g) * HD + f] = *(uint4*)o;
}

// ---------------------------------------------------------------------------
// K7: final — thread per (node, head); head-mean fused via intra-wave shuffle.
// res read as fp16.
// ---------------------------------------------------------------------------
__global__ __launch_bounds__(256) void final_kernel(
    const ushort* __restrict__ t0, const ushort* __restrict__ t1,
    const ushort* __restrict__ t2, const ushort* __restrict__ t3,
    const ushort* __restrict__ resh,
    const float* __restrict__ hal, const float* __restrict__ har,
    const float* __restrict__ w_rel, const float* __restrict__ b_rel,
    float* __restrict__ out)
{
    int idx = blockIdx.x * 256 + threadIdx.x;
    bool active = idx < NN * HH;
    int h_ = idx & 1;
    int n = idx >> 1;
    const ushort* tb[4] = {t0, t1, t2, t3};
    float o[DD];
    #pragma unroll
    for (int d = 0; d < DD; d++) o[d] = 0.f;

    if (active) {
        for (int r = 0; r < RR; r++) {
            float wr = b_rel[r];
            #pragma unroll
            for (int j = 0; j < RR; j++) wr += w_rel[r * RR + j];
            float halc[DD], harc[DD];
            const float4* hp = (const float4*)(hal + (r * HH + h_) * DD);
            const float4* gp = (const float4*)(har + (r * HH + h_) * DD);
            #pragma unroll
            for (int j = 0; j < 8; j++) {
                float4 a = hp[j];
                halc[4 * j] = a.x; halc[4 * j + 1] = a.y; halc[4 * j + 2] = a.z; halc[4 * j + 3] = a.w;
                float4 b = gp[j];
                harc[4 * j] = b.x; harc[4 * j + 1] = b.y; harc[4 * j + 2] = b.z; harc[4 * j + 3] = b.w;
            }
            size_t tbase = ((size_t)r * NN + n) * HD + h_ * DD;
            float sq[4], dl[4], dr = 0.f;
            #pragma unroll
            for (int k = 0; k < 4; k++) {
                const uint2* tp = (const uint2*)(tb[k] + tbase);
                float s = 0.f, d1 = 0.f;
                #pragma unroll
                for (int j = 0; j < 8; j++) {
                    uint2 q = tp[j];
                    float2 v0 = up2(q.x), v1 = up2(q.y);
                    s  += v0.x * v0.x + v0.y * v0.y + v1.x * v1.x + v1.y * v1.y;
                    d1 += v0.x * halc[4 * j] + v0.y * halc[4 * j + 1]
                        + v1.x * halc[4 * j + 2] + v1.y * halc[4 * j + 3];
                    if (k == 0)
                        dr += v0.x * harc[4 * j] + v0.y * harc[4 * j + 1]
                            + v1.x * harc[4 * j + 2] + v1.y * harc[4 * j + 3];
                }
                sq[k] = s; dl[k] = d1;
            }
            float inv[4], lg[4], mx = -1e30f;
            #pragma unroll
            for (int k = 0; k < 4; k++)
                inv[k] = 1.f / fmaxf(sqrtf(sq[k]), 1e-9f);
            #pragma unroll
            for (int k = 0; k < 4; k++) {
                float l = dl[k] * inv[k] + dr * inv[0];
                l = l > 0.f ? l : NEG * l;
                lg[k] = l;
                mx = fmaxf(mx, l);
            }
            float ssum = 0.f;
            #pragma unroll
            for (int k = 0; k < 4; k++) { lg[k] = __expf(lg[k] - mx); ssum += lg[k]; }
            float sw = wr / ssum;
            #pragma unroll
            for (int k = 0; k < 4; k++) {
                float coef = lg[k] * inv[k] * sw;
                const uint2* tp = (const uint2*)(tb[k] + tbase);
                #pragma unroll
                for (int j = 0; j < 8; j++) {
                    uint2 q = tp[j];
                    float2 v0 = up2(q.x), v1 = up2(q.y);
                    o[4 * j]     += coef * v0.x;
                    o[4 * j + 1] += coef * v0.y;
                    o[4 * j + 2] += coef * v1.x;
                    o[4 * j + 3] += coef * v1.y;
                }
            }
            const uint2* rr = (const uint2*)(resh + ((size_t)r * NN + n) * HD + h_ * DD);
            #pragma unroll
            for (int j = 0; j < 8; j++) {
                uint2 q = rr[j];
                float2 v0 = up2(q.x), v1 = up2(q.y);
                o[4 * j]     += wr * v0.x;
                o[4 * j + 1] += wr * v0.y;
                o[4 * j + 2] += wr * v1.x;
                o[4 * j + 3] += wr * v1.y;
            }
        }
    }
    // head-mean: even lane (h=0) pulls odd lane's (h=1) values and writes out.
    float4* op = (float4*)(out + (size_t)n * DD);
    #pragma unroll
    for (int j = 0; j < 8; j++) {
        float x0 = o[4 * j],     x1 = o[4 * j + 1];
        float x2 = o[4 * j + 2], x3 = o[4 * j + 3];
        float y0 = __shfl_down(x0, 1, 64);
        float y1 = __shfl_down(x1, 1, 64);
        float y2 = __shfl_down(x2, 1, 64);
        float y3 = __shfl_down(x3, 1, 64);
        if (active && h_ == 0)
            op[j] = make_float4(0.5f * (x0 + y0), 0.5f * (x1 + y1),
                                0.5f * (x2 + y2), 0.5f * (x3 + y3));
    }
}

// ---------------------------------------------------------------------------
extern "C" void kernel_launch(void* const* d_in, const int* in_sizes, int n_in,
                              void* d_out, int out_size, void* d_ws, size_t ws_size,
                              hipStream_t stream) {
    (void)in_sizes; (void)n_in; (void)out_size; (void)ws_size;
    const float* h     = (const float*)d_in[0];
    const int*   src   = (const int*)d_in[1];
    const int*   dst   = (const int*)d_in[2];
    const float* fcw   = (const float*)d_in[3];
    const float* resw  = (const float*)d_in[4];
    const float* atl   = (const float*)d_in[5];
    const float* atr   = (const float*)d_in[6];
    const float* hal   = (const float*)d_in[7];
    const float* har   = (const float*)d_in[8];
    const float* wrel  = (const float*)d_in[9];
    const float* brel  = (const float*)d_in[10];
    float* out = (float*)d_out;

    float* ws = (float*)d_ws;
    size_t off = 0;
    float* el   = ws + off;  off += (size_t)RR * NN * HH;
    float* er   = ws + off;  off += (size_t)RR * NN * HH;
    uint2* csrE = (uint2*)(ws + off);      off += (size_t)RR * EE * 2;
    unsigned* bucketRec = (unsigned*)(ws + off); off += (size_t)RR * EE;
    ushort* resh = (ushort*)(ws + off);    off += (size_t)RR * NN * HD / 2;
    ushort* t0  = (ushort*)(ws + off);     off += (size_t)RR * NN * HD / 2;
    ushort* t1  = (ushort*)(ws + off);     off += (size_t)RR * NN * HD / 2;
    ushort* t2  = (ushort*)(ws + off);     off += (size_t)RR * NN * HD / 2;
    ushort* t3  = (ushort*)(ws + off);     off += (size_t)RR * NN * HD / 2;
    ushort* wb  = (ushort*)(ws + off);     off += (size_t)RR * 128 * IN / 2;
    int* rowp   = (int*)(ws + off);  off += (size_t)RR * RPS;
    int* blkHist = (int*)(ws + off); off += (size_t)RR * NB * NBLK;
    int* bbase  = (int*)(ws + off);  off += (size_t)RR * (NB + 1);

    cvt_kernel<<<(RR * 128 * IN + 255) / 256, 256, 0, stream>>>(fcw, resw, wb);
    proj_mfma<<<313 * RR, 256, 0, stream>>>(h, wb, t0, resh);
    attn_node_kernel<<<(RR * NN * HH + 255) / 256, 256, 0, stream>>>(t0, atl, atr, el, er);
    bhist_kernel<<<RR * NBLK, 256, 0, stream>>>(dst, blkHist);
    mscan_kernel<<<RR, 256, 0, stream>>>(blkHist, bbase);
    bscatter_kernel<<<RR * NBLK, 256, 0, stream>>>(src, dst, blkHist, bucketRec);
    bsort_alpha_kernel<<<RR * NB, 256, 0, stream>>>(bucketRec, bbase, el, er, csrE, rowp);
    hop_kernel<<<(RR * (NN / 8) + 3) / 4, 256, 0, stream>>>(t0, t1, csrE, rowp);
    hop_kernel<<<(RR * (NN / 8) + 3) / 4, 256, 0, stream>>>(t1, t2, csrE, rowp);
    hop_kernel<<<(RR * (NN / 8) + 3) / 4, 256, 0, stream>>>(t2, t3, csrE, rowp);
    final_kernel<<<(NN * HH + 255) / 256, 256, 0, stream>>>(t0, t1, t2, t3, resh, hal, har, wrel, brel, out);
}

// Round 2
// 265.861 us; speedup vs baseline: 1.0922x; 1.0453x over previous
//
#include <hip/hip_runtime.h>
#include <hip/hip_bf16.h>

#define NN 20000
#define IN 128
#define HH 2
#define DD 32
#define HD 64
#define KK 3
#define RR 5
#define EE 320000
#define NEG 0.2f

#define PADK 136
#define NB 313     // buckets per relation (64 dsts each)
#define NBLK 64    // partition blocks per relation
#define CHUNK 5000 // EE / NBLK
#define CAP 2048   // slots per bucket (mean 1024, sd ~32); stride = 2^11
#define NBCAP (NB * CAP)
#define RPS 20004  // rowp row stride

typedef short v8s __attribute__((ext_vector_type(8)));
typedef float v4f __attribute__((ext_vector_type(4)));
typedef _Float16 hf8 __attribute__((ext_vector_type(8)));

__device__ __forceinline__ ushort f2b(float f) {
    unsigned u = __float_as_uint(f);
    unsigned r = (u + 0x7fff + ((u >> 16) & 1)) >> 16;   // RNE
    return (ushort)r;
}
__device__ __forceinline__ ushort f2h(float f) {
    _Float16 h = (_Float16)f;
    return __builtin_bit_cast(ushort, h);
}
__device__ __forceinline__ float h2f(ushort u) {
    _Float16 h = __builtin_bit_cast(_Float16, u);
    return (float)h;
}
__device__ __forceinline__ float2 up2(unsigned u) {
    return make_float2(h2f((ushort)(u & 0xFFFF)), h2f((ushort)(u >> 16)));
}

// ---------------------------------------------------------------------------
// K0: weights -> wb bf16, transposed+fused: wb[r][col][k], col<64=fc else res.
// Also zeroes the per-bucket edge counters (bcnt) for part_kernel.
// ---------------------------------------------------------------------------
__global__ __launch_bounds__(256) void cvt_kernel(
    const float* __restrict__ fcw, const float* __restrict__ resw,
    ushort* __restrict__ wb, int* __restrict__ bcnt)
{
    int j = blockIdx.x * 256 + threadIdx.x;
    if (j < RR * NB) bcnt[j] = 0;
    if (j >= RR * 128 * IN) return;
    int k = j & 127;
    int c = (j >> 7) & 127;
    int r = j >> 14;
    float v = (c < HD) ? fcw[(r * IN + k) * HD + c] : resw[(r * IN + k) * HD + (c - HD)];
    wb[j] = f2b(v);
}

// ---------------------------------------------------------------------------
// K1: projection via bf16 MFMA; reads fp32 h directly (cvt in staging);
// emits fp16 table t0 (x) and fp16 res.
// Fused attn epilogue: wave 0 holds head-0 cols (0..31), wave 1 head-1 cols
// (32..63) -> el/er computed by 16-lane shfl_xor reduce over fp32 acc.
// ---------------------------------------------------------------------------
__global__ __launch_bounds__(256) void proj_mfma(
    const float* __restrict__ h, const ushort* __restrict__ wb,
    const float* __restrict__ attn_l, const float* __restrict__ attn_r,
    ushort* __restrict__ t0, ushort* __restrict__ resh,
    float* __restrict__ el, float* __restrict__ er)
{
    __shared__ ushort As[64 * PADK];
    __shared__ ushort Bs[128 * PADK];
    int bx = blockIdx.x;
    int r = bx / 313;
    int tile = bx - r * 313;
    int n0 = tile * 64;
    int tid = threadIdx.x;

    // stage A: 64 rows x 128 k, fp32 -> bf16. 2048 float4 chunks / 256 = 8 ea.
    #pragma unroll
    for (int i = 0; i < 8; i++) {
        int c = tid + 256 * i;
        int row = c >> 5;            // 32 float4 per row
        int off = (c & 31) * 4;
        int gn = n0 + row;
        float4 v = make_float4(0.f, 0.f, 0.f, 0.f);
        if (gn < NN) v = *(const float4*)&h[(size_t)gn * IN + off];
        *(ushort4*)&As[row * PADK + off] =
            make_ushort4(f2b(v.x), f2b(v.y), f2b(v.z), f2b(v.w));
    }
    const ushort* wr = wb + (size_t)r * 128 * IN;
    #pragma unroll
    for (int i = 0; i < 8; i++) {
        int c = tid + 256 * i;
        int row = c >> 4;
        int off = (c & 15) * 8;
        *(uint4*)&Bs[row * PADK + off] = *(const uint4*)&wr[row * IN + off];
    }
    __syncthreads();

    int w = tid >> 6, lane = tid & 63;
    int lm = lane & 15, lq = lane >> 4;

    v4f acc[4][2];
    #pragma unroll
    for (int mt = 0; mt < 4; mt++)
        #pragma unroll
        for (int nt = 0; nt < 2; nt++) acc[mt][nt] = (v4f){0.f, 0.f, 0.f, 0.f};

    const ushort* Ab = &As[lm * PADK + lq * 8];
    const ushort* Bb = &Bs[(w * 32 + lm) * PADK + lq * 8];

    #pragma unroll
    for (int ks = 0; ks < 4; ks++) {
        v8s a[4], b[2];
        #pragma unroll
        for (int mt = 0; mt < 4; mt++) a[mt] = *(const v8s*)(Ab + mt * 16 * PADK + ks * 32);
        #pragma unroll
        for (int nt = 0; nt < 2; nt++) b[nt] = *(const v8s*)(Bb + nt * 16 * PADK + ks * 32);
        #pragma unroll
        for (int mt = 0; mt < 4; mt++)
            #pragma unroll
            for (int nt = 0; nt < 2; nt++)
                acc[mt][nt] = __builtin_amdgcn_mfma_f32_16x16x32_bf16(a[mt], b[nt], acc[mt][nt], 0, 0, 0);
    }

    int colbase = w * 32 + lm;
    #pragma unroll
    for (int mt = 0; mt < 4; mt++) {
        #pragma unroll
        for (int nt = 0; nt < 2; nt++) {
            int col = colbase + nt * 16;
            #pragma unroll
            for (int p = 0; p < 4; p++) {
                int node = n0 + mt * 16 + lq * 4 + p;
                if (node < NN) {
                    float v = acc[mt][nt][p];
                    if (col < HD) {
                        t0[((size_t)r * NN + node) * HD + col] = f2h(v);
                    } else {
                        resh[((size_t)r * NN + node) * HD + (col - HD)] = f2h(v);
                    }
                }
            }
        }
    }

    // attn epilogue: wave w<2 computes el/er for head w from fp32 acc.
    if (w < 2) {
        float al0 = attn_l[(r * HH + w) * DD + lm];
        float al1 = attn_l[(r * HH + w) * DD + lm + 16];
        float ar0 = attn_r[(r * HH + w) * DD + lm];
        float ar1 = attn_r[(r * HH + w) * DD + lm + 16];
        #pragma unroll
        for (int mt = 0; mt < 4; mt++) {
            #pragma unroll
            for (int p = 0; p < 4; p++) {
                float pl = acc[mt][0][p] * al0 + acc[mt][1][p] * al1;
                float pr = acc[mt][0][p] * ar0 + acc[mt][1][p] * ar1;
                #pragma unroll
                for (int off = 1; off < 16; off <<= 1) {
                    pl += __shfl_xor(pl, off, 64);
                    pr += __shfl_xor(pr, off, 64);
                }
                if (lm == 0) {
                    int node = n0 + mt * 16 + lq * 4 + p;
                    if (node < NN) {
                        el[((size_t)r * NN + node) * HH + w] = pl;
                        er[((size_t)r * NN + node) * HH + w] = pr;
                    }
                }
            }
        }
    }
}

// ---------------------------------------------------------------------------
// A: fused partition (was bhist+mscan+bscatter): per-chunk LDS histogram ->
// one global atomicAdd per touched bucket reserves a range -> scatter into
// CAP-strided per-bucket slots. Within-bucket order nondeterministic (ok:
// bsort counting-sorts by dst; only fp-sum order within a dst varies).
// ---------------------------------------------------------------------------
__global__ __launch_bounds__(256) void part_kernel(
    const int* __restrict__ src, const int* __restrict__ dst,
    int* __restrict__ bcnt, unsigned* __restrict__ bucketRec)
{
    __shared__ int hh[NB];
    int r = blockIdx.x >> 6;
    int blk = blockIdx.x & 63;
    int tid = threadIdx.x;
    for (int i = tid; i < NB; i += 256) hh[i] = 0;
    __syncthreads();
    const int* S = src + (size_t)r * EE + blk * CHUNK;
    const int* D = dst + (size_t)r * EE + blk * CHUNK;
    for (int i = tid; i < CHUNK; i += 256)
        atomicAdd(&hh[D[i] >> 6], 1);
    __syncthreads();
    for (int i = tid; i < NB; i += 256) {
        int c = hh[i];
        hh[i] = c ? atomicAdd(&bcnt[r * NB + i], c) : 0;
    }
    __syncthreads();
    unsigned* BR = bucketRec + (size_t)r * NBCAP;
    for (int i = tid; i < CHUNK; i += 256) {
        int s = S[i], d = D[i];
        int b = d >> 6;
        int pos = atomicAdd(&hh[b], 1);
        if (pos < CAP)
            BR[((size_t)b << 11) + pos] = (unsigned)s | ((unsigned)(d & 63) << 15);
    }
}

// ---------------------------------------------------------------------------
// B: per-bucket LDS counting sort + exact per-dst softmax -> csrE records
// {src | dstLow<<15, half2(w0,w1)} in CAP-strided slots + packed rowp
// (begin | len<<20), sequential writes.
// ---------------------------------------------------------------------------
__global__ __launch_bounds__(256) void bsort_alpha_kernel(
    const unsigned* __restrict__ bucketRec, const int* __restrict__ bcnt,
    const float* __restrict__ el, const float* __restrict__ er,
    uint2* __restrict__ csrE, int* __restrict__ rowp)
{
    __shared__ int cnt64s[64];
    __shared__ int segS[65];
    __shared__ int cur[64];
    __shared__ float2 erL[64];
    __shared__ float2 mx2[64];
    __shared__ float2 inv2[64];
    __shared__ unsigned sSD[CAP];
    __shared__ float2 sL[CAP];

    int bk = blockIdx.x;            // r*NB + bkt
    int r = bk / NB;
    int bkt = bk - r * NB;
    int tid = threadIdx.x;
    int cnt = bcnt[bk];
    if (cnt > CAP) cnt = CAP;

    if (tid < 64) {
        cnt64s[tid] = 0;
        int gn = bkt * 64 + tid;
        erL[tid] = (gn < NN) ? ((const float2*)er)[(size_t)r * NN + gn]
                             : make_float2(0.f, 0.f);
    }
    __syncthreads();
    const unsigned* BR = bucketRec + (size_t)bk * CAP;
    for (int i = tid; i < cnt; i += 256)
        atomicAdd(&cnt64s[(BR[i] >> 15) & 63], 1);
    __syncthreads();
    if (tid < 64) {
        int v = cnt64s[tid];
        int x = v;
        #pragma unroll
        for (int off = 1; off < 64; off <<= 1) {
            int tt = __shfl_up(x, off, 64);
            if (tid >= off) x += tt;
        }
        segS[tid] = x - v;
        cur[tid] = x - v;
        if (tid == 63) segS[64] = x;
    }
    __syncthreads();
    const float2* el2 = (const float2*)el + (size_t)r * NN;
    for (int i = tid; i < cnt; i += 256) {
        unsigned rec = BR[i];
        int s = rec & 0x7FFF;
        int d = (rec >> 15) & 63;
        float2 a = el2[s];
        float2 b = erL[d];
        float l0 = a.x + b.x; l0 = l0 > 0.f ? l0 : NEG * l0;
        float l1 = a.y + b.y; l1 = l1 > 0.f ? l1 : NEG * l1;
        int pos = atomicAdd(&cur[d], 1);
        sSD[pos] = rec;
        sL[pos] = make_float2(l0, l1);
    }
    __syncthreads();
    if (tid < 64) {
        int b0 = segS[tid], e0 = segS[tid + 1];
        float m0 = -1e30f, m1 = -1e30f;
        for (int i = b0; i < e0; i++) {
            float2 l = sL[i];
            m0 = fmaxf(m0, l.x); m1 = fmaxf(m1, l.y);
        }
        float s0 = 0.f, s1 = 0.f;
        for (int i = b0; i < e0; i++) {
            float2 l = sL[i];
            s0 += __expf(l.x - m0); s1 += __expf(l.y - m1);
        }
        mx2[tid] = make_float2(m0, m1);
        inv2[tid] = make_float2(1.f / fmaxf(s0, 1e-9f), 1.f / fmaxf(s1, 1e-9f));
        int gn = bkt * 64 + tid;
        if (gn < NN) {
            int len = e0 - b0;
            rowp[r * RPS + gn] = (int)(((unsigned)(bkt * CAP + b0)) | ((unsigned)len << 20));
        }
    }
    __syncthreads();
    uint2* E = csrE + (size_t)bk * CAP;
    for (int i = tid; i < cnt; i += 256) {
        unsigned rec = sSD[i];
        int d = (rec >> 15) & 63;
        float2 l = sL[i];
        float w0 = __expf(l.x - mx2[d].x) * inv2[d].x;
        float w1 = __expf(l.y - mx2[d].y) * inv2[d].y;
        E[i] = make_uint2(rec, (unsigned)f2h(w0) | ((unsigned)f2h(w1) << 16));
    }
}

// ---------------------------------------------------------------------------
// K6: diffusion hop, PULL wide-gather: 8 dsts/wave, 8 feats/lane (16 B),
// each dst segment split into TWO interleaved streams -> 4 independent VMEM
// per iteration. XCD-aware bijective block swizzle; v_fma_mix fp16 consume.
// rowp packed begin|len<<20 into CAP-strided csrE; gathered node index
// clamped into [0,NN) so 0-weight gap slots can't inject NaN/Inf.
// ---------------------------------------------------------------------------
__global__ __launch_bounds__(256) void hop_kernel(
    const ushort* __restrict__ tin, ushort* __restrict__ tout,
    const uint2* __restrict__ csrE, const int* __restrict__ rowp)
{
    // bijective XCD swizzle over 8 XCDs (grid = 3125 blocks, 3125 % 8 = 5)
    int nb = gridDim.x;
    int q = nb >> 3, rmd = nb & 7;
    int xcd = blockIdx.x & 7, pos = blockIdx.x >> 3;
    int bid = (xcd < rmd ? xcd * (q + 1) : rmd * (q + 1) + (xcd - rmd) * q) + pos;

    int w = (bid * 256 + (int)threadIdx.x) >> 6;
    if (w >= RR * (NN / 8)) return;
    int lane = threadIdx.x & 63;
    int g = lane >> 3;                 // dst group 0..7
    int f = (lane & 7) * 8;            // feature base 0..56
    int sh = ((lane >> 2) & 1) * 16;   // head select: f>=32 <=> bit2 of lane
    int r = w / (NN / 8);
    int n0 = (w - r * (NN / 8)) * 8;

    unsigned pv = (unsigned)rowp[r * RPS + n0 + g];
    int bg = (int)(pv & 0xFFFFF);
    int len = (int)(pv >> 20);
    int eg = bg + len;
    int cl = (len + 1) >> 1;           // stream A length (ceil half)
    int b2 = bg + cl;                  // stream B start

    int m = cl;
    m = max(m, __shfl_xor(m, 8, 64));
    m = max(m, __shfl_xor(m, 16, 64));
    m = max(m, __shfl_xor(m, 32, 64));

    int lastA = bg + cl - 1;
    lastA = lastA > bg ? lastA : bg;
    int lastB = eg - 1;
    lastB = lastB > b2 ? lastB : b2;

    const ushort* T = tin + (size_t)r * NN * HD;
    const uint2* E = csrE + (size_t)r * NBCAP;

    float accA[8] = {0.f, 0.f, 0.f, 0.f, 0.f, 0.f, 0.f, 0.f};
    float accB[8] = {0.f, 0.f, 0.f, 0.f, 0.f, 0.f, 0.f, 0.f};
    #pragma unroll 4
    for (int j = 0; j < m; j++) {
        int ia = bg + j;
        int iac = ia < lastA ? ia : lastA;
        int ib = b2 + j;
        int ibc = ib < lastB ? ib : lastB;
        uint2 ra = E[iac];
        uint2 rb = E[ibc];
        float wa = (j < cl) ? h2f((ushort)(ra.y >> sh)) : 0.f;
        float wb = (ib < eg) ? h2f((ushort)(rb.y >> sh)) : 0.f;
        int na = (int)(ra.x & 0x7FFF); na = na < NN ? na : 0;
        int nbv = (int)(rb.x & 0x7FFF); nbv = nbv < NN ? nbv : 0;
        hf8 va = *(const hf8*)&T[(size_t)na * HD + f];
        hf8 vb = *(const hf8*)&T[(size_t)nbv * HD + f];
        #pragma unroll
        for (int k2 = 0; k2 < 8; k2++) {
            accA[k2] += wa * (float)va[k2];
            accB[k2] += wb * (float)vb[k2];
        }
    }
    ushort o[8];
    #pragma unroll
    for (int k = 0; k < 8; k++) o[k] = f2h(accA[k] + accB[k]);
    *(uint4*)&tout[((size_t)r * NN + n0 + g) * HD + f] = *(uint4*)o;
}

// ---------------------------------------------------------------------------
// K7: final — thread per (node, head); head-mean fused via intra-wave shuffle.
// res read as fp16.
// ---------------------------------------------------------------------------
__global__ __launch_bounds__(256) void final_kernel(
    const ushort* __restrict__ t0, const ushort* __restrict__ t1,
    const ushort* __restrict__ t2, const ushort* __restrict__ t3,
    const ushort* __restrict__ resh,
    const float* __restrict__ hal, const float* __restrict__ har,
    const float* __restrict__ w_rel, const float* __restrict__ b_rel,
    float* __restrict__ out)
{
    int idx = blockIdx.x * 256 + threadIdx.x;
    bool active = idx < NN * HH;
    int h_ = idx & 1;
    int n = idx >> 1;
    const ushort* tb[4] = {t0, t1, t2, t3};
    float o[DD];
    #pragma unroll
    for (int d = 0; d < DD; d++) o[d] = 0.f;

    if (active) {
        for (int r = 0; r < RR; r++) {
            float wr = b_rel[r];
            #pragma unroll
            for (int j = 0; j < RR; j++) wr += w_rel[r * RR + j];
            float halc[DD], harc[DD];
            const float4* hp = (const float4*)(hal + (r * HH + h_) * DD);
            const float4* gp = (const float4*)(har + (r * HH + h_) * DD);
            #pragma unroll
            for (int j = 0; j < 8; j++) {
                float4 a = hp[j];
                halc[4 * j] = a.x; halc[4 * j + 1] = a.y; halc[4 * j + 2] = a.z; halc[4 * j + 3] = a.w;
                float4 b = gp[j];
                harc[4 * j] = b.x; harc[4 * j + 1] = b.y; harc[4 * j + 2] = b.z; harc[4 * j + 3] = b.w;
            }
            size_t tbase = ((size_t)r * NN + n) * HD + h_ * DD;
            float sq[4], dl[4], dr = 0.f;
            #pragma unroll
            for (int k = 0; k < 4; k++) {
                const uint2* tp = (const uint2*)(tb[k] + tbase);
                float s = 0.f, d1 = 0.f;
                #pragma unroll
                for (int j = 0; j < 8; j++) {
                    uint2 q = tp[j];
                    float2 v0 = up2(q.x), v1 = up2(q.y);
                    s  += v0.x * v0.x + v0.y * v0.y + v1.x * v1.x + v1.y * v1.y;
                    d1 += v0.x * halc[4 * j] + v0.y * halc[4 * j + 1]
                        + v1.x * halc[4 * j + 2] + v1.y * halc[4 * j + 3];
                    if (k == 0)
                        dr += v0.x * harc[4 * j] + v0.y * harc[4 * j + 1]
                            + v1.x * harc[4 * j + 2] + v1.y * harc[4 * j + 3];
                }
                sq[k] = s; dl[k] = d1;
            }
            float inv[4], lg[4], mx = -1e30f;
            #pragma unroll
            for (int k = 0; k < 4; k++)
                inv[k] = 1.f / fmaxf(sqrtf(sq[k]), 1e-9f);
            #pragma unroll
            for (int k = 0; k < 4; k++) {
                float l = dl[k] * inv[k] + dr * inv[0];
                l = l > 0.f ? l : NEG * l;
                lg[k] = l;
                mx = fmaxf(mx, l);
            }
            float ssum = 0.f;
            #pragma unroll
            for (int k = 0; k < 4; k++) { lg[k] = __expf(lg[k] - mx); ssum += lg[k]; }
            float sw = wr / ssum;
            #pragma unroll
            for (int k = 0; k < 4; k++) {
                float coef = lg[k] * inv[k] * sw;
                const uint2* tp = (const uint2*)(tb[k] + tbase);
                #pragma unroll
                for (int j = 0; j < 8; j++) {
                    uint2 q = tp[j];
                    float2 v0 = up2(q.x), v1 = up2(q.y);
                    o[4 * j]     += coef * v0.x;
                    o[4 * j + 1] += coef * v0.y;
                    o[4 * j + 2] += coef * v1.x;
                    o[4 * j + 3] += coef * v1.y;
                }
            }
            const uint2* rr = (const uint2*)(resh + ((size_t)r * NN + n) * HD + h_ * DD);
            #pragma unroll
            for (int j = 0; j < 8; j++) {
                uint2 q = rr[j];
                float2 v0 = up2(q.x), v1 = up2(q.y);
                o[4 * j]     += wr * v0.x;
                o[4 * j + 1] += wr * v0.y;
                o[4 * j + 2] += wr * v1.x;
                o[4 * j + 3] += wr * v1.y;
            }
        }
    }
    // head-mean: even lane (h=0) pulls odd lane's (h=1) values and writes out.
    float4* op = (float4*)(out + (size_t)n * DD);
    #pragma unroll
    for (int j = 0; j < 8; j++) {
        float x0 = o[4 * j],     x1 = o[4 * j + 1];
        float x2 = o[4 * j + 2], x3 = o[4 * j + 3];
        float y0 = __shfl_down(x0, 1, 64);
        float y1 = __shfl_down(x1, 1, 64);
        float y2 = __shfl_down(x2, 1, 64);
        float y3 = __shfl_down(x3, 1, 64);
        if (active && h_ == 0)
            op[j] = make_float4(0.5f * (x0 + y0), 0.5f * (x1 + y1),
                                0.5f * (x2 + y2), 0.5f * (x3 + y3));
    }
}

// ---------------------------------------------------------------------------
extern "C" void kernel_launch(void* const* d_in, const int* in_sizes, int n_in,
                              void* d_out, int out_size, void* d_ws, size_t ws_size,
                              hipStream_t stream) {
    (void)in_sizes; (void)n_in; (void)out_size; (void)ws_size;
    const float* h     = (const float*)d_in[0];
    const int*   src   = (const int*)d_in[1];
    const int*   dst   = (const int*)d_in[2];
    const float* fcw   = (const float*)d_in[3];
    const float* resw  = (const float*)d_in[4];
    const float* atl   = (const float*)d_in[5];
    const float* atr   = (const float*)d_in[6];
    const float* hal   = (const float*)d_in[7];
    const float* har   = (const float*)d_in[8];
    const float* wrel  = (const float*)d_in[9];
    const float* brel  = (const float*)d_in[10];
    float* out = (float*)d_out;

    float* ws = (float*)d_ws;
    size_t off = 0;
    float* el   = ws + off;  off += (size_t)RR * NN * HH;
    float* er   = ws + off;  off += (size_t)RR * NN * HH;
    uint2* csrE = (uint2*)(ws + off);      off += (size_t)RR * NBCAP * 2;
    unsigned* bucketRec = (unsigned*)(ws + off); off += (size_t)RR * NBCAP;
    ushort* resh = (ushort*)(ws + off);    off += (size_t)RR * NN * HD / 2;
    ushort* t0  = (ushort*)(ws + off);     off += (size_t)RR * NN * HD / 2;
    ushort* t1  = (ushort*)(ws + off);     off += (size_t)RR * NN * HD / 2;
    ushort* t2  = (ushort*)(ws + off);     off += (size_t)RR * NN * HD / 2;
    ushort* t3  = (ushort*)(ws + off);     off += (size_t)RR * NN * HD / 2;
    ushort* wb  = (ushort*)(ws + off);     off += (size_t)RR * 128 * IN / 2;
    int* rowp   = (int*)(ws + off);  off += (size_t)RR * RPS;
    int* bcnt   = (int*)(ws + off);  off += (size_t)RR * NB;

    cvt_kernel<<<(RR * 128 * IN + 255) / 256, 256, 0, stream>>>(fcw, resw, wb, bcnt);
    proj_mfma<<<313 * RR, 256, 0, stream>>>(h, wb, atl, atr, t0, resh, el, er);
    part_kernel<<<RR * NBLK, 256, 0, stream>>>(src, dst, bcnt, bucketRec);
    bsort_alpha_kernel<<<RR * NB, 256, 0, stream>>>(bucketRec, bcnt, el, er, csrE, rowp);
    hop_kernel<<<(RR * (NN / 8) + 3) / 4, 256, 0, stream>>>(t0, t1, csrE, rowp);
    hop_kernel<<<(RR * (NN / 8) + 3) / 4, 256, 0, stream>>>(t1, t2, csrE, rowp);
    hop_kernel<<<(RR * (NN / 8) + 3) / 4, 256, 0, stream>>>(t2, t3, csrE, rowp);
    final_kernel<<<(NN * HH + 255) / 256, 256, 0, stream>>>(t0, t1, t2, t3, resh, hal, har, wrel, brel, out);
}

// Round 3
// 249.506 us; speedup vs baseline: 1.1637x; 1.0655x over previous
//
#include <hip/hip_runtime.h>
#include <hip/hip_bf16.h>

#define NN 20000
#define IN 128
#define HH 2
#define DD 32
#define HD 64
#define KK 3
#define RR 5
#define EE 320000
#define NEG 0.2f

#define PADK 136
#define NB 313     // buckets per relation (64 dsts each)
#define NBLK 64    // partition blocks per relation
#define CHUNK 5000 // EE / NBLK
#define CAP 2048   // slots per bucket (mean 1024, sd ~32); stride = 2^11
#define NBCAP (NB * CAP)
#define RPS 20004  // rowp row stride

typedef short v8s __attribute__((ext_vector_type(8)));
typedef float v4f __attribute__((ext_vector_type(4)));
typedef _Float16 hf8 __attribute__((ext_vector_type(8)));

__device__ __forceinline__ ushort f2b(float f) {
    unsigned u = __float_as_uint(f);
    unsigned r = (u + 0x7fff + ((u >> 16) & 1)) >> 16;   // RNE
    return (ushort)r;
}
__device__ __forceinline__ ushort f2h(float f) {
    _Float16 h = (_Float16)f;
    return __builtin_bit_cast(ushort, h);
}
__device__ __forceinline__ float h2f(ushort u) {
    _Float16 h = __builtin_bit_cast(_Float16, u);
    return (float)h;
}
__device__ __forceinline__ float2 up2(unsigned u) {
    return make_float2(h2f((ushort)(u & 0xFFFF)), h2f((ushort)(u >> 16)));
}

// ---------------------------------------------------------------------------
// K0: weights -> wb bf16, transposed+fused: wb[r][col][k], col<64=fc else res.
// Also zeroes the per-bucket edge counters (bcnt) for part_kernel.
// ---------------------------------------------------------------------------
__global__ __launch_bounds__(256) void cvt_kernel(
    const float* __restrict__ fcw, const float* __restrict__ resw,
    ushort* __restrict__ wb, int* __restrict__ bcnt)
{
    int j = blockIdx.x * 256 + threadIdx.x;
    if (j < RR * NB) bcnt[j] = 0;
    if (j >= RR * 128 * IN) return;
    int k = j & 127;
    int c = (j >> 7) & 127;
    int r = j >> 14;
    float v = (c < HD) ? fcw[(r * IN + k) * HD + c] : resw[(r * IN + k) * HD + (c - HD)];
    wb[j] = f2b(v);
}

// ---------------------------------------------------------------------------
// K1: projection via bf16 MFMA; reads fp32 h directly (cvt in staging);
// emits fp16 table t0 (x) and fp16 res.
// Fused attn epilogue: wave 0 holds head-0 cols (0..31), wave 1 head-1 cols
// (32..63) -> el/er computed by 16-lane shfl_xor reduce over fp32 acc.
// ---------------------------------------------------------------------------
__global__ __launch_bounds__(256) void proj_mfma(
    const float* __restrict__ h, const ushort* __restrict__ wb,
    const float* __restrict__ attn_l, const float* __restrict__ attn_r,
    ushort* __restrict__ t0, ushort* __restrict__ resh,
    float* __restrict__ el, float* __restrict__ er)
{
    __shared__ ushort As[64 * PADK];
    __shared__ ushort Bs[128 * PADK];
    int bx = blockIdx.x;
    int r = bx / 313;
    int tile = bx - r * 313;
    int n0 = tile * 64;
    int tid = threadIdx.x;

    // stage A: 64 rows x 128 k, fp32 -> bf16. 2048 float4 chunks / 256 = 8 ea.
    #pragma unroll
    for (int i = 0; i < 8; i++) {
        int c = tid + 256 * i;
        int row = c >> 5;            // 32 float4 per row
        int off = (c & 31) * 4;
        int gn = n0 + row;
        float4 v = make_float4(0.f, 0.f, 0.f, 0.f);
        if (gn < NN) v = *(const float4*)&h[(size_t)gn * IN + off];
        *(ushort4*)&As[row * PADK + off] =
            make_ushort4(f2b(v.x), f2b(v.y), f2b(v.z), f2b(v.w));
    }
    const ushort* wr = wb + (size_t)r * 128 * IN;
    #pragma unroll
    for (int i = 0; i < 8; i++) {
        int c = tid + 256 * i;
        int row = c >> 4;
        int off = (c & 15) * 8;
        *(uint4*)&Bs[row * PADK + off] = *(const uint4*)&wr[row * IN + off];
    }
    __syncthreads();

    int w = tid >> 6, lane = tid & 63;
    int lm = lane & 15, lq = lane >> 4;

    v4f acc[4][2];
    #pragma unroll
    for (int mt = 0; mt < 4; mt++)
        #pragma unroll
        for (int nt = 0; nt < 2; nt++) acc[mt][nt] = (v4f){0.f, 0.f, 0.f, 0.f};

    const ushort* Ab = &As[lm * PADK + lq * 8];
    const ushort* Bb = &Bs[(w * 32 + lm) * PADK + lq * 8];

    #pragma unroll
    for (int ks = 0; ks < 4; ks++) {
        v8s a[4], b[2];
        #pragma unroll
        for (int mt = 0; mt < 4; mt++) a[mt] = *(const v8s*)(Ab + mt * 16 * PADK + ks * 32);
        #pragma unroll
        for (int nt = 0; nt < 2; nt++) b[nt] = *(const v8s*)(Bb + nt * 16 * PADK + ks * 32);
        #pragma unroll
        for (int mt = 0; mt < 4; mt++)
            #pragma unroll
            for (int nt = 0; nt < 2; nt++)
                acc[mt][nt] = __builtin_amdgcn_mfma_f32_16x16x32_bf16(a[mt], b[nt], acc[mt][nt], 0, 0, 0);
    }

    int colbase = w * 32 + lm;
    #pragma unroll
    for (int mt = 0; mt < 4; mt++) {
        #pragma unroll
        for (int nt = 0; nt < 2; nt++) {
            int col = colbase + nt * 16;
            #pragma unroll
            for (int p = 0; p < 4; p++) {
                int node = n0 + mt * 16 + lq * 4 + p;
                if (node < NN) {
                    float v = acc[mt][nt][p];
                    if (col < HD) {
                        t0[((size_t)r * NN + node) * HD + col] = f2h(v);
                    } else {
                        resh[((size_t)r * NN + node) * HD + (col - HD)] = f2h(v);
                    }
                }
            }
        }
    }

    // attn epilogue: wave w<2 computes el/er for head w from fp32 acc.
    if (w < 2) {
        float al0 = attn_l[(r * HH + w) * DD + lm];
        float al1 = attn_l[(r * HH + w) * DD + lm + 16];
        float ar0 = attn_r[(r * HH + w) * DD + lm];
        float ar1 = attn_r[(r * HH + w) * DD + lm + 16];
        #pragma unroll
        for (int mt = 0; mt < 4; mt++) {
            #pragma unroll
            for (int p = 0; p < 4; p++) {
                float pl = acc[mt][0][p] * al0 + acc[mt][1][p] * al1;
                float pr = acc[mt][0][p] * ar0 + acc[mt][1][p] * ar1;
                #pragma unroll
                for (int off = 1; off < 16; off <<= 1) {
                    pl += __shfl_xor(pl, off, 64);
                    pr += __shfl_xor(pr, off, 64);
                }
                if (lm == 0) {
                    int node = n0 + mt * 16 + lq * 4 + p;
                    if (node < NN) {
                        el[((size_t)r * NN + node) * HH + w] = pl;
                        er[((size_t)r * NN + node) * HH + w] = pr;
                    }
                }
            }
        }
    }
}

// ---------------------------------------------------------------------------
// A: fused partition: per-chunk LDS histogram -> one global atomicAdd per
// touched bucket reserves a range -> scatter into CAP-strided slots.
// ---------------------------------------------------------------------------
__global__ __launch_bounds__(256) void part_kernel(
    const int* __restrict__ src, const int* __restrict__ dst,
    int* __restrict__ bcnt, unsigned* __restrict__ bucketRec)
{
    __shared__ int hh[NB];
    int r = blockIdx.x >> 6;
    int blk = blockIdx.x & 63;
    int tid = threadIdx.x;
    for (int i = tid; i < NB; i += 256) hh[i] = 0;
    __syncthreads();
    const int* S = src + (size_t)r * EE + blk * CHUNK;
    const int* D = dst + (size_t)r * EE + blk * CHUNK;
    for (int i = tid; i < CHUNK; i += 256)
        atomicAdd(&hh[D[i] >> 6], 1);
    __syncthreads();
    for (int i = tid; i < NB; i += 256) {
        int c = hh[i];
        hh[i] = c ? atomicAdd(&bcnt[r * NB + i], c) : 0;
    }
    __syncthreads();
    unsigned* BR = bucketRec + (size_t)r * NBCAP;
    for (int i = tid; i < CHUNK; i += 256) {
        int s = S[i], d = D[i];
        int b = d >> 6;
        int pos = atomicAdd(&hh[b], 1);
        if (pos < CAP)
            BR[((size_t)b << 11) + pos] = (unsigned)s | ((unsigned)(d & 63) << 15);
    }
}

// ---------------------------------------------------------------------------
// B: per-bucket LDS counting sort + exact per-dst softmax -> csrE records
// {src | dstLow<<15, half2(w0,w1)} in CAP-strided slots + packed rowp
// (begin | len<<20). v2: softmax phase wave-parallel (4 threads per dst,
// shfl_xor reduce) instead of 64-serial-lane (Common-mistake #6 fix).
// ---------------------------------------------------------------------------
__global__ __launch_bounds__(256) void bsort_alpha_kernel(
    const unsigned* __restrict__ bucketRec, const int* __restrict__ bcnt,
    const float* __restrict__ el, const float* __restrict__ er,
    uint2* __restrict__ csrE, int* __restrict__ rowp)
{
    __shared__ int cnt64s[64];
    __shared__ int segS[65];
    __shared__ int cur[64];
    __shared__ float2 erL[64];
    __shared__ float2 mx2[64];
    __shared__ float2 inv2[64];
    __shared__ unsigned sSD[CAP];
    __shared__ float2 sL[CAP];

    int bk = blockIdx.x;            // r*NB + bkt
    int r = bk / NB;
    int bkt = bk - r * NB;
    int tid = threadIdx.x;
    int cnt = bcnt[bk];
    if (cnt > CAP) cnt = CAP;

    if (tid < 64) {
        cnt64s[tid] = 0;
        int gn = bkt * 64 + tid;
        erL[tid] = (gn < NN) ? ((const float2*)er)[(size_t)r * NN + gn]
                             : make_float2(0.f, 0.f);
    }
    __syncthreads();
    const unsigned* BR = bucketRec + (size_t)bk * CAP;
    for (int i = tid; i < cnt; i += 256)
        atomicAdd(&cnt64s[(BR[i] >> 15) & 63], 1);
    __syncthreads();
    if (tid < 64) {
        int v = cnt64s[tid];
        int x = v;
        #pragma unroll
        for (int off = 1; off < 64; off <<= 1) {
            int tt = __shfl_up(x, off, 64);
            if (tid >= off) x += tt;
        }
        segS[tid] = x - v;
        cur[tid] = x - v;
        if (tid == 63) segS[64] = x;
    }
    __syncthreads();
    const float2* el2 = (const float2*)el + (size_t)r * NN;
    for (int i = tid; i < cnt; i += 256) {
        unsigned rec = BR[i];
        int s = rec & 0x7FFF;
        int d = (rec >> 15) & 63;
        float2 a = el2[s];
        float2 b = erL[d];
        float l0 = a.x + b.x; l0 = l0 > 0.f ? l0 : NEG * l0;
        float l1 = a.y + b.y; l1 = l1 > 0.f ? l1 : NEG * l1;
        int pos = atomicAdd(&cur[d], 1);
        sSD[pos] = rec;
        sL[pos] = make_float2(l0, l1);
    }
    __syncthreads();
    // wave-parallel per-dst softmax: 4 threads per dst, shfl_xor(1,2) reduce
    {
        int d = tid >> 2, sub = tid & 3;
        int b0 = segS[d], e0 = segS[d + 1];
        float m0 = -1e30f, m1 = -1e30f;
        for (int i = b0 + sub; i < e0; i += 4) {
            float2 l = sL[i];
            m0 = fmaxf(m0, l.x); m1 = fmaxf(m1, l.y);
        }
        m0 = fmaxf(m0, __shfl_xor(m0, 1, 64));
        m0 = fmaxf(m0, __shfl_xor(m0, 2, 64));
        m1 = fmaxf(m1, __shfl_xor(m1, 1, 64));
        m1 = fmaxf(m1, __shfl_xor(m1, 2, 64));
        float s0 = 0.f, s1 = 0.f;
        for (int i = b0 + sub; i < e0; i += 4) {
            float2 l = sL[i];
            s0 += __expf(l.x - m0); s1 += __expf(l.y - m1);
        }
        s0 += __shfl_xor(s0, 1, 64); s0 += __shfl_xor(s0, 2, 64);
        s1 += __shfl_xor(s1, 1, 64); s1 += __shfl_xor(s1, 2, 64);
        if (sub == 0) {
            mx2[d] = make_float2(m0, m1);
            inv2[d] = make_float2(1.f / fmaxf(s0, 1e-9f), 1.f / fmaxf(s1, 1e-9f));
            int gn = bkt * 64 + d;
            if (gn < NN) {
                int len = e0 - b0;
                rowp[r * RPS + gn] = (int)(((unsigned)(bkt * CAP + b0)) | ((unsigned)len << 20));
            }
        }
    }
    __syncthreads();
    uint2* E = csrE + (size_t)bk * CAP;
    for (int i = tid; i < cnt; i += 256) {
        unsigned rec = sSD[i];
        int d = (rec >> 15) & 63;
        float2 l = sL[i];
        float w0 = __expf(l.x - mx2[d].x) * inv2[d].x;
        float w1 = __expf(l.y - mx2[d].y) * inv2[d].y;
        E[i] = make_uint2(rec, (unsigned)f2h(w0) | ((unsigned)f2h(w1) << 16));
    }
}

// ---------------------------------------------------------------------------
// K6: diffusion hop, PULL wide-gather: 8 dsts/wave, 8 feats/lane (16 B),
// two interleaved streams per dst segment; XCD-aware bijective swizzle;
// v_fma_mix fp16 consume; clamped gather index for gap slots.
// ---------------------------------------------------------------------------
__global__ __launch_bounds__(256) void hop_kernel(
    const ushort* __restrict__ tin, ushort* __restrict__ tout,
    const uint2* __restrict__ csrE, const int* __restrict__ rowp)
{
    int nb = gridDim.x;
    int q = nb >> 3, rmd = nb & 7;
    int xcd = blockIdx.x & 7, pos = blockIdx.x >> 3;
    int bid = (xcd < rmd ? xcd * (q + 1) : rmd * (q + 1) + (xcd - rmd) * q) + pos;

    int w = (bid * 256 + (int)threadIdx.x) >> 6;
    if (w >= RR * (NN / 8)) return;
    int lane = threadIdx.x & 63;
    int g = lane >> 3;                 // dst group 0..7
    int f = (lane & 7) * 8;            // feature base 0..56
    int sh = ((lane >> 2) & 1) * 16;   // head select: f>=32 <=> bit2 of lane
    int r = w / (NN / 8);
    int n0 = (w - r * (NN / 8)) * 8;

    unsigned pv = (unsigned)rowp[r * RPS + n0 + g];
    int bg = (int)(pv & 0xFFFFF);
    int len = (int)(pv >> 20);
    int eg = bg + len;
    int cl = (len + 1) >> 1;           // stream A length (ceil half)
    int b2 = bg + cl;                  // stream B start

    int m = cl;
    m = max(m, __shfl_xor(m, 8, 64));
    m = max(m, __shfl_xor(m, 16, 64));
    m = max(m, __shfl_xor(m, 32, 64));

    int lastA = bg + cl - 1;
    lastA = lastA > bg ? lastA : bg;
    int lastB = eg - 1;
    lastB = lastB > b2 ? lastB : b2;

    const ushort* T = tin + (size_t)r * NN * HD;
    const uint2* E = csrE + (size_t)r * NBCAP;

    float accA[8] = {0.f, 0.f, 0.f, 0.f, 0.f, 0.f, 0.f, 0.f};
    float accB[8] = {0.f, 0.f, 0.f, 0.f, 0.f, 0.f, 0.f, 0.f};
    #pragma unroll 4
    for (int j = 0; j < m; j++) {
        int ia = bg + j;
        int iac = ia < lastA ? ia : lastA;
        int ib = b2 + j;
        int ibc = ib < lastB ? ib : lastB;
        uint2 ra = E[iac];
        uint2 rb = E[ibc];
        float wa = (j < cl) ? h2f((ushort)(ra.y >> sh)) : 0.f;
        float wb = (ib < eg) ? h2f((ushort)(rb.y >> sh)) : 0.f;
        int na = (int)(ra.x & 0x7FFF); na = na < NN ? na : 0;
        int nbv = (int)(rb.x & 0x7FFF); nbv = nbv < NN ? nbv : 0;
        hf8 va = *(const hf8*)&T[(size_t)na * HD + f];
        hf8 vb = *(const hf8*)&T[(size_t)nbv * HD + f];
        #pragma unroll
        for (int k2 = 0; k2 < 8; k2++) {
            accA[k2] += wa * (float)va[k2];
            accB[k2] += wb * (float)vb[k2];
        }
    }
    ushort o[8];
    #pragma unroll
    for (int k = 0; k < 8; k++) o[k] = f2h(accA[k] + accB[k]);
    *(uint4*)&tout[((size_t)r * NN + n0 + g) * HD + f] = *(uint4*)o;
}

// ---------------------------------------------------------------------------
// K7 v2: final — 4 lanes per (node, head), 8 feats/lane (one uint4 per hop
// table). 160k threads (was 40k): 4x occupancy, 4x shorter load chains.
// sq/dl/dr reduced across the 4 lanes via shfl_xor(1,2); head-mean via
// shfl_down(4).
// ---------------------------------------------------------------------------
__global__ __launch_bounds__(256) void final_kernel(
    const ushort* __restrict__ t0, const ushort* __restrict__ t1,
    const ushort* __restrict__ t2, const ushort* __restrict__ t3,
    const ushort* __restrict__ resh,
    const float* __restrict__ hal, const float* __restrict__ har,
    const float* __restrict__ w_rel, const float* __restrict__ b_rel,
    float* __restrict__ out)
{
    int idx = blockIdx.x * 256 + threadIdx.x;   // over NN*HH*4 = 160000
    if (idx >= NN * HH * 4) return;
    int fq = idx & 3;                 // feature quarter: feats [fq*8, fq*8+8)
    int h_ = (idx >> 2) & 1;
    int n = idx >> 3;
    const ushort* tb[4] = {t0, t1, t2, t3};
    float o[8];
    #pragma unroll
    for (int d = 0; d < 8; d++) o[d] = 0.f;

    for (int r = 0; r < RR; r++) {
        float wr = b_rel[r];
        #pragma unroll
        for (int j = 0; j < RR; j++) wr += w_rel[r * RR + j];
        const float* hp = hal + (r * HH + h_) * DD + fq * 8;
        const float* gp = har + (r * HH + h_) * DD + fq * 8;
        float4 ha0 = *(const float4*)hp;
        float4 ha1 = *(const float4*)(hp + 4);
        float4 hr0 = *(const float4*)gp;
        float4 hr1 = *(const float4*)(gp + 4);
        float halc[8] = {ha0.x, ha0.y, ha0.z, ha0.w, ha1.x, ha1.y, ha1.z, ha1.w};
        float harc[8] = {hr0.x, hr0.y, hr0.z, hr0.w, hr1.x, hr1.y, hr1.z, hr1.w};

        size_t tbase = ((size_t)r * NN + n) * HD + h_ * DD + fq * 8;
        uint4 tv[4];
        float sq[4], dl[4], dr = 0.f;
        #pragma unroll
        for (int k = 0; k < 4; k++) {
            tv[k] = *(const uint4*)(tb[k] + tbase);
            unsigned ww[4] = {tv[k].x, tv[k].y, tv[k].z, tv[k].w};
            float s = 0.f, d1 = 0.f;
            #pragma unroll
            for (int j = 0; j < 4; j++) {
                float2 v = up2(ww[j]);
                s  += v.x * v.x + v.y * v.y;
                d1 += v.x * halc[2 * j] + v.y * halc[2 * j + 1];
                if (k == 0)
                    dr += v.x * harc[2 * j] + v.y * harc[2 * j + 1];
            }
            sq[k] = s; dl[k] = d1;
        }
        // reduce partial dots across the 4 lanes sharing (n, h_)
        #pragma unroll
        for (int k = 0; k < 4; k++) {
            sq[k] += __shfl_xor(sq[k], 1, 64); sq[k] += __shfl_xor(sq[k], 2, 64);
            dl[k] += __shfl_xor(dl[k], 1, 64); dl[k] += __shfl_xor(dl[k], 2, 64);
        }
        dr += __shfl_xor(dr, 1, 64); dr += __shfl_xor(dr, 2, 64);

        float inv[4], lg[4], mx = -1e30f;
        #pragma unroll
        for (int k = 0; k < 4; k++)
            inv[k] = 1.f / fmaxf(sqrtf(sq[k]), 1e-9f);
        #pragma unroll
        for (int k = 0; k < 4; k++) {
            float l = dl[k] * inv[k] + dr * inv[0];
            l = l > 0.f ? l : NEG * l;
            lg[k] = l;
            mx = fmaxf(mx, l);
        }
        float ssum = 0.f;
        #pragma unroll
        for (int k = 0; k < 4; k++) { lg[k] = __expf(lg[k] - mx); ssum += lg[k]; }
        float sw = wr / ssum;
        #pragma unroll
        for (int k = 0; k < 4; k++) {
            float coef = lg[k] * inv[k] * sw;
            unsigned ww[4] = {tv[k].x, tv[k].y, tv[k].z, tv[k].w};
            #pragma unroll
            for (int j = 0; j < 4; j++) {
                float2 v = up2(ww[j]);
                o[2 * j]     += coef * v.x;
                o[2 * j + 1] += coef * v.y;
            }
        }
        uint4 rv = *(const uint4*)(resh + tbase);
        unsigned rw[4] = {rv.x, rv.y, rv.z, rv.w};
        #pragma unroll
        for (int j = 0; j < 4; j++) {
            float2 v = up2(rw[j]);
            o[2 * j]     += wr * v.x;
            o[2 * j + 1] += wr * v.y;
        }
    }
    // head-mean: h=0 lane pulls h=1 lane (4 apart) and writes out.
    float p[8];
    #pragma unroll
    for (int j = 0; j < 8; j++) p[j] = __shfl_down(o[j], 4, 64);
    if (h_ == 0) {
        float4* op = (float4*)(out + (size_t)n * DD + fq * 8);
        op[0] = make_float4(0.5f * (o[0] + p[0]), 0.5f * (o[1] + p[1]),
                            0.5f * (o[2] + p[2]), 0.5f * (o[3] + p[3]));
        op[1] = make_float4(0.5f * (o[4] + p[4]), 0.5f * (o[5] + p[5]),
                            0.5f * (o[6] + p[6]), 0.5f * (o[7] + p[7]));
    }
}

// ---------------------------------------------------------------------------
extern "C" void kernel_launch(void* const* d_in, const int* in_sizes, int n_in,
                              void* d_out, int out_size, void* d_ws, size_t ws_size,
                              hipStream_t stream) {
    (void)in_sizes; (void)n_in; (void)out_size; (void)ws_size;
    const float* h     = (const float*)d_in[0];
    const int*   src   = (const int*)d_in[1];
    const int*   dst   = (const int*)d_in[2];
    const float* fcw   = (const float*)d_in[3];
    const float* resw  = (const float*)d_in[4];
    const float* atl   = (const float*)d_in[5];
    const float* atr   = (const float*)d_in[6];
    const float* hal   = (const float*)d_in[7];
    const float* har   = (const float*)d_in[8];
    const float* wrel  = (const float*)d_in[9];
    const float* brel  = (const float*)d_in[10];
    float* out = (float*)d_out;

    float* ws = (float*)d_ws;
    size_t off = 0;
    float* el   = ws + off;  off += (size_t)RR * NN * HH;
    float* er   = ws + off;  off += (size_t)RR * NN * HH;
    uint2* csrE = (uint2*)(ws + off);      off += (size_t)RR * NBCAP * 2;
    unsigned* bucketRec = (unsigned*)(ws + off); off += (size_t)RR * NBCAP;
    ushort* resh = (ushort*)(ws + off);    off += (size_t)RR * NN * HD / 2;
    ushort* t0  = (ushort*)(ws + off);     off += (size_t)RR * NN * HD / 2;
    ushort* t1  = (ushort*)(ws + off);     off += (size_t)RR * NN * HD / 2;
    ushort* t2  = (ushort*)(ws + off);     off += (size_t)RR * NN * HD / 2;
    ushort* t3  = (ushort*)(ws + off);     off += (size_t)RR * NN * HD / 2;
    ushort* wb  = (ushort*)(ws + off);     off += (size_t)RR * 128 * IN / 2;
    int* rowp   = (int*)(ws + off);  off += (size_t)RR * RPS;
    int* bcnt   = (int*)(ws + off);  off += (size_t)RR * NB;

    cvt_kernel<<<(RR * 128 * IN + 255) / 256, 256, 0, stream>>>(fcw, resw, wb, bcnt);
    proj_mfma<<<313 * RR, 256, 0, stream>>>(h, wb, atl, atr, t0, resh, el, er);
    part_kernel<<<RR * NBLK, 256, 0, stream>>>(src, dst, bcnt, bucketRec);
    bsort_alpha_kernel<<<RR * NB, 256, 0, stream>>>(bucketRec, bcnt, el, er, csrE, rowp);
    hop_kernel<<<(RR * (NN / 8) + 3) / 4, 256, 0, stream>>>(t0, t1, csrE, rowp);
    hop_kernel<<<(RR * (NN / 8) + 3) / 4, 256, 0, stream>>>(t1, t2, csrE, rowp);
    hop_kernel<<<(RR * (NN / 8) + 3) / 4, 256, 0, stream>>>(t2, t3, csrE, rowp);
    final_kernel<<<(NN * HH * 4 + 255) / 256, 256, 0, stream>>>(t0, t1, t2, t3, resh, hal, har, wrel, brel, out);
}

// Round 4
// 236.428 us; speedup vs baseline: 1.2281x; 1.0553x over previous
//
#include <hip/hip_runtime.h>
#include <hip/hip_bf16.h>

#define NN 20000
#define IN 128
#define HH 2
#define DD 32
#define HD 64
#define KK 3
#define RR 5
#define EE 320000
#define NEG 0.2f

#define PADK 136
#define NB 313     // buckets per relation (64 dsts each)
#define NBLK 64    // partition blocks per relation
#define CHUNK 5000 // EE / NBLK
#define CAP 2048   // slots per bucket (mean 1024, sd ~32); stride = 2^11
#define NBCAP (NB * CAP)
#define RPS 20004  // rowp row stride
#define HTOT (NN * IN / 4)   // float4 chunks of h

typedef short v8s __attribute__((ext_vector_type(8)));
typedef float v4f __attribute__((ext_vector_type(4)));
typedef _Float16 hf8 __attribute__((ext_vector_type(8)));

__device__ __forceinline__ ushort f2b(float f) {
    unsigned u = __float_as_uint(f);
    unsigned r = (u + 0x7fff + ((u >> 16) & 1)) >> 16;   // RNE
    return (ushort)r;
}
__device__ __forceinline__ ushort f2h(float f) {
    _Float16 h = (_Float16)f;
    return __builtin_bit_cast(ushort, h);
}
__device__ __forceinline__ float h2f(ushort u) {
    _Float16 h = __builtin_bit_cast(_Float16, u);
    return (float)h;
}
__device__ __forceinline__ float2 up2(unsigned u) {
    return make_float2(h2f((ushort)(u & 0xFFFF)), h2f((ushort)(u >> 16)));
}

// ---------------------------------------------------------------------------
// K0: weights -> wb bf16 (transposed+fused), h -> hb bf16 (once, so proj
// staging is half the bytes and zero converts), bcnt zeroing.
// ---------------------------------------------------------------------------
__global__ __launch_bounds__(256) void cvt_kernel(
    const float* __restrict__ h, const float* __restrict__ fcw,
    const float* __restrict__ resw, ushort* __restrict__ wb,
    ushort* __restrict__ hb, int* __restrict__ bcnt)
{
    int j = blockIdx.x * 256 + threadIdx.x;
    if (j < RR * NB) bcnt[j] = 0;
    if (j < RR * 128 * IN) {
        int k = j & 127;
        int c = (j >> 7) & 127;
        int r = j >> 14;
        float v = (c < HD) ? fcw[(r * IN + k) * HD + c] : resw[(r * IN + k) * HD + (c - HD)];
        wb[j] = f2b(v);
    }
    int t = j - RR * 128 * IN;
    if (t >= 0 && t < HTOT) {
        float4 v = ((const float4*)h)[t];
        ((ushort4*)hb)[t] = make_ushort4(f2b(v.x), f2b(v.y), f2b(v.z), f2b(v.w));
    }
}

// ---------------------------------------------------------------------------
// K1: projection via bf16 MFMA; reads pre-converted bf16 hb; emits fp16
// table t0 (x) and fp16 res. Fused attn epilogue (el/er) from fp32 acc.
// ---------------------------------------------------------------------------
__global__ __launch_bounds__(256) void proj_mfma(
    const ushort* __restrict__ hb, const ushort* __restrict__ wb,
    const float* __restrict__ attn_l, const float* __restrict__ attn_r,
    ushort* __restrict__ t0, ushort* __restrict__ resh,
    float* __restrict__ el, float* __restrict__ er)
{
    __shared__ ushort As[64 * PADK];
    __shared__ ushort Bs[128 * PADK];
    int bx = blockIdx.x;
    int r = bx / 313;
    int tile = bx - r * 313;
    int n0 = tile * 64;
    int tid = threadIdx.x;

    // stage A: 64 rows x 128 k bf16. 1024 uint4 chunks / 256 = 4 ea.
    #pragma unroll
    for (int i = 0; i < 4; i++) {
        int c = tid + 256 * i;
        int row = c >> 4;            // 16 uint4 per row
        int off = (c & 15) * 8;
        int gn = n0 + row;
        uint4 v = make_uint4(0u, 0u, 0u, 0u);
        if (gn < NN) v = *(const uint4*)&hb[(size_t)gn * IN + off];
        *(uint4*)&As[row * PADK + off] = v;
    }
    const ushort* wr = wb + (size_t)r * 128 * IN;
    #pragma unroll
    for (int i = 0; i < 8; i++) {
        int c = tid + 256 * i;
        int row = c >> 4;
        int off = (c & 15) * 8;
        *(uint4*)&Bs[row * PADK + off] = *(const uint4*)&wr[row * IN + off];
    }
    __syncthreads();

    int w = tid >> 6, lane = tid & 63;
    int lm = lane & 15, lq = lane >> 4;

    v4f acc[4][2];
    #pragma unroll
    for (int mt = 0; mt < 4; mt++)
        #pragma unroll
        for (int nt = 0; nt < 2; nt++) acc[mt][nt] = (v4f){0.f, 0.f, 0.f, 0.f};

    const ushort* Ab = &As[lm * PADK + lq * 8];
    const ushort* Bb = &Bs[(w * 32 + lm) * PADK + lq * 8];

    #pragma unroll
    for (int ks = 0; ks < 4; ks++) {
        v8s a[4], b[2];
        #pragma unroll
        for (int mt = 0; mt < 4; mt++) a[mt] = *(const v8s*)(Ab + mt * 16 * PADK + ks * 32);
        #pragma unroll
        for (int nt = 0; nt < 2; nt++) b[nt] = *(const v8s*)(Bb + nt * 16 * PADK + ks * 32);
        #pragma unroll
        for (int mt = 0; mt < 4; mt++)
            #pragma unroll
            for (int nt = 0; nt < 2; nt++)
                acc[mt][nt] = __builtin_amdgcn_mfma_f32_16x16x32_bf16(a[mt], b[nt], acc[mt][nt], 0, 0, 0);
    }

    int colbase = w * 32 + lm;
    #pragma unroll
    for (int mt = 0; mt < 4; mt++) {
        #pragma unroll
        for (int nt = 0; nt < 2; nt++) {
            int col = colbase + nt * 16;
            #pragma unroll
            for (int p = 0; p < 4; p++) {
                int node = n0 + mt * 16 + lq * 4 + p;
                if (node < NN) {
                    float v = acc[mt][nt][p];
                    if (col < HD) {
                        t0[((size_t)r * NN + node) * HD + col] = f2h(v);
                    } else {
                        resh[((size_t)r * NN + node) * HD + (col - HD)] = f2h(v);
                    }
                }
            }
        }
    }

    // attn epilogue: wave w<2 computes el/er for head w from fp32 acc.
    if (w < 2) {
        float al0 = attn_l[(r * HH + w) * DD + lm];
        float al1 = attn_l[(r * HH + w) * DD + lm + 16];
        float ar0 = attn_r[(r * HH + w) * DD + lm];
        float ar1 = attn_r[(r * HH + w) * DD + lm + 16];
        #pragma unroll
        for (int mt = 0; mt < 4; mt++) {
            #pragma unroll
            for (int p = 0; p < 4; p++) {
                float pl = acc[mt][0][p] * al0 + acc[mt][1][p] * al1;
                float pr = acc[mt][0][p] * ar0 + acc[mt][1][p] * ar1;
                #pragma unroll
                for (int off = 1; off < 16; off <<= 1) {
                    pl += __shfl_xor(pl, off, 64);
                    pr += __shfl_xor(pr, off, 64);
                }
                if (lm == 0) {
                    int node = n0 + mt * 16 + lq * 4 + p;
                    if (node < NN) {
                        el[((size_t)r * NN + node) * HH + w] = pl;
                        er[((size_t)r * NN + node) * HH + w] = pr;
                    }
                }
            }
        }
    }
}

// ---------------------------------------------------------------------------
// A: fused partition: per-chunk LDS histogram -> one global atomicAdd per
// touched bucket reserves a range -> scatter into CAP-strided slots.
// ---------------------------------------------------------------------------
__global__ __launch_bounds__(256) void part_kernel(
    const int* __restrict__ src, const int* __restrict__ dst,
    int* __restrict__ bcnt, unsigned* __restrict__ bucketRec)
{
    __shared__ int hh[NB];
    int r = blockIdx.x >> 6;
    int blk = blockIdx.x & 63;
    int tid = threadIdx.x;
    for (int i = tid; i < NB; i += 256) hh[i] = 0;
    __syncthreads();
    const int* S = src + (size_t)r * EE + blk * CHUNK;
    const int* D = dst + (size_t)r * EE + blk * CHUNK;
    for (int i = tid; i < CHUNK; i += 256)
        atomicAdd(&hh[D[i] >> 6], 1);
    __syncthreads();
    for (int i = tid; i < NB; i += 256) {
        int c = hh[i];
        hh[i] = c ? atomicAdd(&bcnt[r * NB + i], c) : 0;
    }
    __syncthreads();
    unsigned* BR = bucketRec + (size_t)r * NBCAP;
    for (int i = tid; i < CHUNK; i += 256) {
        int s = S[i], d = D[i];
        int b = d >> 6;
        int pos = atomicAdd(&hh[b], 1);
        if (pos < CAP)
            BR[((size_t)b << 11) + pos] = (unsigned)s | ((unsigned)(d & 63) << 15);
    }
}

// ---------------------------------------------------------------------------
// B: per-bucket LDS counting sort + exact per-dst softmax -> csrE records.
// v3: per-wave sub-histograms (4x less LDS-atomic same-address contention);
// wave-parallel softmax (4 threads/dst).
// ---------------------------------------------------------------------------
__global__ __launch_bounds__(256) void bsort_alpha_kernel(
    const unsigned* __restrict__ bucketRec, const int* __restrict__ bcnt,
    const float* __restrict__ el, const float* __restrict__ er,
    uint2* __restrict__ csrE, int* __restrict__ rowp)
{
    __shared__ int cnt64s[4][64];
    __shared__ int segS[65];
    __shared__ int cur[64];
    __shared__ float2 erL[64];
    __shared__ float2 mx2[64];
    __shared__ float2 inv2[64];
    __shared__ unsigned sSD[CAP];
    __shared__ float2 sL[CAP];

    int bk = blockIdx.x;            // r*NB + bkt
    int r = bk / NB;
    int bkt = bk - r * NB;
    int tid = threadIdx.x;
    int wv = tid >> 6;
    int cnt = bcnt[bk];
    if (cnt > CAP) cnt = CAP;

    if (tid < 64) {
        cnt64s[0][tid] = 0; cnt64s[1][tid] = 0;
        cnt64s[2][tid] = 0; cnt64s[3][tid] = 0;
        int gn = bkt * 64 + tid;
        erL[tid] = (gn < NN) ? ((const float2*)er)[(size_t)r * NN + gn]
                             : make_float2(0.f, 0.f);
    }
    __syncthreads();
    const unsigned* BR = bucketRec + (size_t)bk * CAP;
    for (int i = tid; i < cnt; i += 256)
        atomicAdd(&cnt64s[wv][(BR[i] >> 15) & 63], 1);
    __syncthreads();
    if (tid < 64) {
        int v = cnt64s[0][tid] + cnt64s[1][tid] + cnt64s[2][tid] + cnt64s[3][tid];
        int x = v;
        #pragma unroll
        for (int off = 1; off < 64; off <<= 1) {
            int tt = __shfl_up(x, off, 64);
            if (tid >= off) x += tt;
        }
        segS[tid] = x - v;
        cur[tid] = x - v;
        if (tid == 63) segS[64] = x;
    }
    __syncthreads();
    const float2* el2 = (const float2*)el + (size_t)r * NN;
    for (int i = tid; i < cnt; i += 256) {
        unsigned rec = BR[i];
        int s = rec & 0x7FFF;
        int d = (rec >> 15) & 63;
        float2 a = el2[s];
        float2 b = erL[d];
        float l0 = a.x + b.x; l0 = l0 > 0.f ? l0 : NEG * l0;
        float l1 = a.y + b.y; l1 = l1 > 0.f ? l1 : NEG * l1;
        int pos = atomicAdd(&cur[d], 1);
        sSD[pos] = rec;
        sL[pos] = make_float2(l0, l1);
    }
    __syncthreads();
    // wave-parallel per-dst softmax: 4 threads per dst, shfl_xor(1,2) reduce
    {
        int d = tid >> 2, sub = tid & 3;
        int b0 = segS[d], e0 = segS[d + 1];
        float m0 = -1e30f, m1 = -1e30f;
        for (int i = b0 + sub; i < e0; i += 4) {
            float2 l = sL[i];
            m0 = fmaxf(m0, l.x); m1 = fmaxf(m1, l.y);
        }
        m0 = fmaxf(m0, __shfl_xor(m0, 1, 64));
        m0 = fmaxf(m0, __shfl_xor(m0, 2, 64));
        m1 = fmaxf(m1, __shfl_xor(m1, 1, 64));
        m1 = fmaxf(m1, __shfl_xor(m1, 2, 64));
        float s0 = 0.f, s1 = 0.f;
        for (int i = b0 + sub; i < e0; i += 4) {
            float2 l = sL[i];
            s0 += __expf(l.x - m0); s1 += __expf(l.y - m1);
        }
        s0 += __shfl_xor(s0, 1, 64); s0 += __shfl_xor(s0, 2, 64);
        s1 += __shfl_xor(s1, 1, 64); s1 += __shfl_xor(s1, 2, 64);
        if (sub == 0) {
            mx2[d] = make_float2(m0, m1);
            inv2[d] = make_float2(1.f / fmaxf(s0, 1e-9f), 1.f / fmaxf(s1, 1e-9f));
            int gn = bkt * 64 + d;
            if (gn < NN) {
                int len = e0 - b0;
                rowp[r * RPS + gn] = (int)(((unsigned)(bkt * CAP + b0)) | ((unsigned)len << 20));
            }
        }
    }
    __syncthreads();
    uint2* E = csrE + (size_t)bk * CAP;
    for (int i = tid; i < cnt; i += 256) {
        unsigned rec = sSD[i];
        int d = (rec >> 15) & 63;
        float2 l = sL[i];
        float w0 = __expf(l.x - mx2[d].x) * inv2[d].x;
        float w1 = __expf(l.y - mx2[d].y) * inv2[d].y;
        E[i] = make_uint2(rec, (unsigned)f2h(w0) | ((unsigned)f2h(w1) << 16));
    }
}

// ---------------------------------------------------------------------------
// K6 v5: diffusion hop, PULL wide-gather, 8 dsts/wave, 8 feats/lane, dual
// stream per dst + EXPLICIT 2-stage register pipeline: csrE records
// prefetched 2 iterations ahead, feature gathers 1 ahead (T14 issue-early /
// consume-late) so the dependent-gather chain (rec ~200cy -> feat ~200cy)
// is covered by the previous iteration's FMA body across resident waves.
// ---------------------------------------------------------------------------
__global__ __launch_bounds__(256) void hop_kernel(
    const ushort* __restrict__ tin, ushort* __restrict__ tout,
    const uint2* __restrict__ csrE, const int* __restrict__ rowp)
{
    int nbk = gridDim.x;
    int q = nbk >> 3, rmd = nbk & 7;
    int xcd = blockIdx.x & 7, pos = blockIdx.x >> 3;
    int bid = (xcd < rmd ? xcd * (q + 1) : rmd * (q + 1) + (xcd - rmd) * q) + pos;

    int w = (bid * 256 + (int)threadIdx.x) >> 6;
    if (w >= RR * (NN / 8)) return;
    int lane = threadIdx.x & 63;
    int g = lane >> 3;                 // dst group 0..7
    int f = (lane & 7) * 8;            // feature base 0..56
    int sh = ((lane >> 2) & 1) * 16;   // head select: f>=32 <=> bit2 of lane
    int r = w / (NN / 8);
    int n0 = (w - r * (NN / 8)) * 8;

    unsigned pv = (unsigned)rowp[r * RPS + n0 + g];
    int bg = (int)(pv & 0xFFFFF);
    int len = (int)(pv >> 20);
    int eg = bg + len;
    int cl = (len + 1) >> 1;           // stream A length (ceil half)
    int b2 = bg + cl;                  // stream B start

    int m = cl;
    m = max(m, __shfl_xor(m, 8, 64));
    m = max(m, __shfl_xor(m, 16, 64));
    m = max(m, __shfl_xor(m, 32, 64));

    int lastA = bg + cl - 1;
    lastA = lastA > bg ? lastA : bg;
    int lastB = eg - 1;
    lastB = lastB > b2 ? lastB : b2;

    const ushort* T = tin + (size_t)r * NN * HD;
    const uint2* E = csrE + (size_t)r * NBCAP;

    // pipeline prologue: recs for j=0, j=1; features for j=0
    int iA0 = bg < lastA ? bg : lastA;
    int iA1 = bg + 1 < lastA ? bg + 1 : lastA;
    int iB0 = b2 < lastB ? b2 : lastB;
    int iB1 = b2 + 1 < lastB ? b2 + 1 : lastB;
    uint2 raC = E[iA0], rbC = E[iB0];
    uint2 raN = E[iA1], rbN = E[iB1];
    int na0 = (int)(raC.x & 0x7FFF); na0 = na0 < NN ? na0 : 0;
    int nb0 = (int)(rbC.x & 0x7FFF); nb0 = nb0 < NN ? nb0 : 0;
    hf8 fa = *(const hf8*)&T[(size_t)na0 * HD + f];
    hf8 fb = *(const hf8*)&T[(size_t)nb0 * HD + f];

    float accA[8] = {0.f, 0.f, 0.f, 0.f, 0.f, 0.f, 0.f, 0.f};
    float accB[8] = {0.f, 0.f, 0.f, 0.f, 0.f, 0.f, 0.f, 0.f};
    #pragma unroll 2
    for (int j = 0; j < m; j++) {
        // issue rec loads for j+2
        int ja = bg + j + 2; ja = ja < lastA ? ja : lastA;
        int jb = b2 + j + 2; jb = jb < lastB ? jb : lastB;
        uint2 ra2 = E[ja];
        uint2 rb2 = E[jb];
        // issue feature loads for j+1 (addresses from raN/rbN)
        int na1 = (int)(raN.x & 0x7FFF); na1 = na1 < NN ? na1 : 0;
        int nb1 = (int)(rbN.x & 0x7FFF); nb1 = nb1 < NN ? nb1 : 0;
        hf8 fa1 = *(const hf8*)&T[(size_t)na1 * HD + f];
        hf8 fb1 = *(const hf8*)&T[(size_t)nb1 * HD + f];
        // consume current
        float wa = (j < cl) ? h2f((ushort)(raC.y >> sh)) : 0.f;
        float wb = (b2 + j < eg) ? h2f((ushort)(rbC.y >> sh)) : 0.f;
        #pragma unroll
        for (int k2 = 0; k2 < 8; k2++) {
            accA[k2] += wa * (float)fa[k2];
            accB[k2] += wb * (float)fb[k2];
        }
        // rotate
        raC = raN; raN = ra2;
        rbC = rbN; rbN = rb2;
        fa = fa1; fb = fb1;
    }
    ushort o[8];
    #pragma unroll
    for (int k = 0; k < 8; k++) o[k] = f2h(accA[k] + accB[k]);
    *(uint4*)&tout[((size_t)r * NN + n0 + g) * HD + f] = *(uint4*)o;
}

// ---------------------------------------------------------------------------
// K7 v2: final — 4 lanes per (node, head), 8 feats/lane; partial dots
// reduced via shfl_xor(1,2); head-mean via shfl_down(4).
// ---------------------------------------------------------------------------
__global__ __launch_bounds__(256) void final_kernel(
    const ushort* __restrict__ t0, const ushort* __restrict__ t1,
    const ushort* __restrict__ t2, const ushort* __restrict__ t3,
    const ushort* __restrict__ resh,
    const float* __restrict__ hal, const float* __restrict__ har,
    const float* __restrict__ w_rel, const float* __restrict__ b_rel,
    float* __restrict__ out)
{
    int idx = blockIdx.x * 256 + threadIdx.x;   // over NN*HH*4 = 160000
    if (idx >= NN * HH * 4) return;
    int fq = idx & 3;                 // feature quarter: feats [fq*8, fq*8+8)
    int h_ = (idx >> 2) & 1;
    int n = idx >> 3;
    const ushort* tb[4] = {t0, t1, t2, t3};
    float o[8];
    #pragma unroll
    for (int d = 0; d < 8; d++) o[d] = 0.f;

    for (int r = 0; r < RR; r++) {
        float wr = b_rel[r];
        #pragma unroll
        for (int j = 0; j < RR; j++) wr += w_rel[r * RR + j];
        const float* hp = hal + (r * HH + h_) * DD + fq * 8;
        const float* gp = har + (r * HH + h_) * DD + fq * 8;
        float4 ha0 = *(const float4*)hp;
        float4 ha1 = *(const float4*)(hp + 4);
        float4 hr0 = *(const float4*)gp;
        float4 hr1 = *(const float4*)(gp + 4);
        float halc[8] = {ha0.x, ha0.y, ha0.z, ha0.w, ha1.x, ha1.y, ha1.z, ha1.w};
        float harc[8] = {hr0.x, hr0.y, hr0.z, hr0.w, hr1.x, hr1.y, hr1.z, hr1.w};

        size_t tbase = ((size_t)r * NN + n) * HD + h_ * DD + fq * 8;
        uint4 tv[4];
        float sq[4], dl[4], dr = 0.f;
        #pragma unroll
        for (int k = 0; k < 4; k++) {
            tv[k] = *(const uint4*)(tb[k] + tbase);
            unsigned ww[4] = {tv[k].x, tv[k].y, tv[k].z, tv[k].w};
            float s = 0.f, d1 = 0.f;
            #pragma unroll
            for (int j = 0; j < 4; j++) {
                float2 v = up2(ww[j]);
                s  += v.x * v.x + v.y * v.y;
                d1 += v.x * halc[2 * j] + v.y * halc[2 * j + 1];
                if (k == 0)
                    dr += v.x * harc[2 * j] + v.y * harc[2 * j + 1];
            }
            sq[k] = s; dl[k] = d1;
        }
        #pragma unroll
        for (int k = 0; k < 4; k++) {
            sq[k] += __shfl_xor(sq[k], 1, 64); sq[k] += __shfl_xor(sq[k], 2, 64);
            dl[k] += __shfl_xor(dl[k], 1, 64); dl[k] += __shfl_xor(dl[k], 2, 64);
        }
        dr += __shfl_xor(dr, 1, 64); dr += __shfl_xor(dr, 2, 64);

        float inv[4], lg[4], mx = -1e30f;
        #pragma unroll
        for (int k = 0; k < 4; k++)
            inv[k] = 1.f / fmaxf(sqrtf(sq[k]), 1e-9f);
        #pragma unroll
        for (int k = 0; k < 4; k++) {
            float l = dl[k] * inv[k] + dr * inv[0];
            l = l > 0.f ? l : NEG * l;
            lg[k] = l;
            mx = fmaxf(mx, l);
        }
        float ssum = 0.f;
        #pragma unroll
        for (int k = 0; k < 4; k++) { lg[k] = __expf(lg[k] - mx); ssum += lg[k]; }
        float sw = wr / ssum;
        #pragma unroll
        for (int k = 0; k < 4; k++) {
            float coef = lg[k] * inv[k] * sw;
            unsigned ww[4] = {tv[k].x, tv[k].y, tv[k].z, tv[k].w};
            #pragma unroll
            for (int j = 0; j < 4; j++) {
                float2 v = up2(ww[j]);
                o[2 * j]     += coef * v.x;
                o[2 * j + 1] += coef * v.y;
            }
        }
        uint4 rv = *(const uint4*)(resh + tbase);
        unsigned rw[4] = {rv.x, rv.y, rv.z, rv.w};
        #pragma unroll
        for (int j = 0; j < 4; j++) {
            float2 v = up2(rw[j]);
            o[2 * j]     += wr * v.x;
            o[2 * j + 1] += wr * v.y;
        }
    }
    // head-mean: h=0 lane pulls h=1 lane (4 apart) and writes out.
    float p[8];
    #pragma unroll
    for (int j = 0; j < 8; j++) p[j] = __shfl_down(o[j], 4, 64);
    if (h_ == 0) {
        float4* op = (float4*)(out + (size_t)n * DD + fq * 8);
        op[0] = make_float4(0.5f * (o[0] + p[0]), 0.5f * (o[1] + p[1]),
                            0.5f * (o[2] + p[2]), 0.5f * (o[3] + p[3]));
        op[1] = make_float4(0.5f * (o[4] + p[4]), 0.5f * (o[5] + p[5]),
                            0.5f * (o[6] + p[6]), 0.5f * (o[7] + p[7]));
    }
}

// ---------------------------------------------------------------------------
extern "C" void kernel_launch(void* const* d_in, const int* in_sizes, int n_in,
                              void* d_out, int out_size, void* d_ws, size_t ws_size,
                              hipStream_t stream) {
    (void)in_sizes; (void)n_in; (void)out_size; (void)ws_size;
    const float* h     = (const float*)d_in[0];
    const int*   src   = (const int*)d_in[1];
    const int*   dst   = (const int*)d_in[2];
    const float* fcw   = (const float*)d_in[3];
    const float* resw  = (const float*)d_in[4];
    const float* atl   = (const float*)d_in[5];
    const float* atr   = (const float*)d_in[6];
    const float* hal   = (const float*)d_in[7];
    const float* har   = (const float*)d_in[8];
    const float* wrel  = (const float*)d_in[9];
    const float* brel  = (const float*)d_in[10];
    float* out = (float*)d_out;

    float* ws = (float*)d_ws;
    size_t off = 0;
    float* el   = ws + off;  off += (size_t)RR * NN * HH;
    float* er   = ws + off;  off += (size_t)RR * NN * HH;
    uint2* csrE = (uint2*)(ws + off);      off += (size_t)RR * NBCAP * 2;
    unsigned* bucketRec = (unsigned*)(ws + off); off += (size_t)RR * NBCAP;
    ushort* resh = (ushort*)(ws + off);    off += (size_t)RR * NN * HD / 2;
    ushort* t0  = (ushort*)(ws + off);     off += (size_t)RR * NN * HD / 2;
    ushort* t1  = (ushort*)(ws + off);     off += (size_t)RR * NN * HD / 2;
    ushort* t2  = (ushort*)(ws + off);     off += (size_t)RR * NN * HD / 2;
    ushort* t3  = (ushort*)(ws + off);     off += (size_t)RR * NN * HD / 2;
    ushort* wb  = (ushort*)(ws + off);     off += (size_t)RR * 128 * IN / 2;
    ushort* hb  = (ushort*)(ws + off);     off += (size_t)NN * IN / 2;
    int* rowp   = (int*)(ws + off);  off += (size_t)RR * RPS;
    int* bcnt   = (int*)(ws + off);  off += (size_t)RR * NB;

    cvt_kernel<<<(RR * 128 * IN + HTOT + 255) / 256, 256, 0, stream>>>(h, fcw, resw, wb, hb, bcnt);
    proj_mfma<<<313 * RR, 256, 0, stream>>>(hb, wb, atl, atr, t0, resh, el, er);
    part_kernel<<<RR * NBLK, 256, 0, stream>>>(src, dst, bcnt, bucketRec);
    bsort_alpha_kernel<<<RR * NB, 256, 0, stream>>>(bucketRec, bcnt, el, er, csrE, rowp);
    hop_kernel<<<(RR * (NN / 8) + 3) / 4, 256, 0, stream>>>(t0, t1, csrE, rowp);
    hop_kernel<<<(RR * (NN / 8) + 3) / 4, 256, 0, stream>>>(t1, t2, csrE, rowp);
    hop_kernel<<<(RR * (NN / 8) + 3) / 4, 256, 0, stream>>>(t2, t3, csrE, rowp);
    final_kernel<<<(NN * HH * 4 + 255) / 256, 256, 0, stream>>>(t0, t1, t2, t3, resh, hal, har, wrel, brel, out);
}

// Round 5
// 236.031 us; speedup vs baseline: 1.2302x; 1.0017x over previous
//
#include <hip/hip_runtime.h>
#include <hip/hip_bf16.h>

#define NN 20000
#define IN 128
#define HH 2
#define DD 32
#define HD 64
#define KK 3
#define RR 5
#define EE 320000
#define NEG 0.2f

#define PADK 136
#define NB 313     // buckets per relation (64 dsts each)
#define NBLK 64    // partition blocks per relation
#define CHUNK 5000 // EE / NBLK
#define CAP 2048   // slots per bucket (mean 1024, sd ~32); stride = 2^11
#define NBCAP (NB * CAP)
#define RPS 20004  // rowp row stride
#define HTOT (NN * IN / 4)   // float4 chunks of h

typedef short v8s __attribute__((ext_vector_type(8)));
typedef float v4f __attribute__((ext_vector_type(4)));
typedef _Float16 hf8 __attribute__((ext_vector_type(8)));

__device__ __forceinline__ ushort f2b(float f) {
    unsigned u = __float_as_uint(f);
    unsigned r = (u + 0x7fff + ((u >> 16) & 1)) >> 16;   // RNE
    return (ushort)r;
}
__device__ __forceinline__ ushort f2h(float f) {
    _Float16 h = (_Float16)f;
    return __builtin_bit_cast(ushort, h);
}
__device__ __forceinline__ float h2f(ushort u) {
    _Float16 h = __builtin_bit_cast(_Float16, u);
    return (float)h;
}
__device__ __forceinline__ float2 up2(unsigned u) {
    return make_float2(h2f((ushort)(u & 0xFFFF)), h2f((ushort)(u >> 16)));
}

// ---------------------------------------------------------------------------
// K0: weights -> wb bf16 (transposed+fused), h -> hb bf16 (once, so proj
// staging is half the bytes and zero converts), bcnt zeroing.
// ---------------------------------------------------------------------------
__global__ __launch_bounds__(256) void cvt_kernel(
    const float* __restrict__ h, const float* __restrict__ fcw,
    const float* __restrict__ resw, ushort* __restrict__ wb,
    ushort* __restrict__ hb, int* __restrict__ bcnt)
{
    int j = blockIdx.x * 256 + threadIdx.x;
    if (j < RR * NB) bcnt[j] = 0;
    if (j < RR * 128 * IN) {
        int k = j & 127;
        int c = (j >> 7) & 127;
        int r = j >> 14;
        float v = (c < HD) ? fcw[(r * IN + k) * HD + c] : resw[(r * IN + k) * HD + (c - HD)];
        wb[j] = f2b(v);
    }
    int t = j - RR * 128 * IN;
    if (t >= 0 && t < HTOT) {
        float4 v = ((const float4*)h)[t];
        ((ushort4*)hb)[t] = make_ushort4(f2b(v.x), f2b(v.y), f2b(v.z), f2b(v.w));
    }
}

// ---------------------------------------------------------------------------
// K1: projection via bf16 MFMA; reads pre-converted bf16 hb; emits fp16
// table t0 (x) and fp16 res. Fused attn epilogue (el/er) from fp32 acc.
// ---------------------------------------------------------------------------
__global__ __launch_bounds__(256) void proj_mfma(
    const ushort* __restrict__ hb, const ushort* __restrict__ wb,
    const float* __restrict__ attn_l, const float* __restrict__ attn_r,
    ushort* __restrict__ t0, ushort* __restrict__ resh,
    float* __restrict__ el, float* __restrict__ er)
{
    __shared__ ushort As[64 * PADK];
    __shared__ ushort Bs[128 * PADK];
    int bx = blockIdx.x;
    int r = bx / 313;
    int tile = bx - r * 313;
    int n0 = tile * 64;
    int tid = threadIdx.x;

    // stage A: 64 rows x 128 k bf16. 1024 uint4 chunks / 256 = 4 ea.
    #pragma unroll
    for (int i = 0; i < 4; i++) {
        int c = tid + 256 * i;
        int row = c >> 4;            // 16 uint4 per row
        int off = (c & 15) * 8;
        int gn = n0 + row;
        uint4 v = make_uint4(0u, 0u, 0u, 0u);
        if (gn < NN) v = *(const uint4*)&hb[(size_t)gn * IN + off];
        *(uint4*)&As[row * PADK + off] = v;
    }
    const ushort* wr = wb + (size_t)r * 128 * IN;
    #pragma unroll
    for (int i = 0; i < 8; i++) {
        int c = tid + 256 * i;
        int row = c >> 4;
        int off = (c & 15) * 8;
        *(uint4*)&Bs[row * PADK + off] = *(const uint4*)&wr[row * IN + off];
    }
    __syncthreads();

    int w = tid >> 6, lane = tid & 63;
    int lm = lane & 15, lq = lane >> 4;

    v4f acc[4][2];
    #pragma unroll
    for (int mt = 0; mt < 4; mt++)
        #pragma unroll
        for (int nt = 0; nt < 2; nt++) acc[mt][nt] = (v4f){0.f, 0.f, 0.f, 0.f};

    const ushort* Ab = &As[lm * PADK + lq * 8];
    const ushort* Bb = &Bs[(w * 32 + lm) * PADK + lq * 8];

    #pragma unroll
    for (int ks = 0; ks < 4; ks++) {
        v8s a[4], b[2];
        #pragma unroll
        for (int mt = 0; mt < 4; mt++) a[mt] = *(const v8s*)(Ab + mt * 16 * PADK + ks * 32);
        #pragma unroll
        for (int nt = 0; nt < 2; nt++) b[nt] = *(const v8s*)(Bb + nt * 16 * PADK + ks * 32);
        #pragma unroll
        for (int mt = 0; mt < 4; mt++)
            #pragma unroll
            for (int nt = 0; nt < 2; nt++)
                acc[mt][nt] = __builtin_amdgcn_mfma_f32_16x16x32_bf16(a[mt], b[nt], acc[mt][nt], 0, 0, 0);
    }

    int colbase = w * 32 + lm;
    #pragma unroll
    for (int mt = 0; mt < 4; mt++) {
        #pragma unroll
        for (int nt = 0; nt < 2; nt++) {
            int col = colbase + nt * 16;
            #pragma unroll
            for (int p = 0; p < 4; p++) {
                int node = n0 + mt * 16 + lq * 4 + p;
                if (node < NN) {
                    float v = acc[mt][nt][p];
                    if (col < HD) {
                        t0[((size_t)r * NN + node) * HD + col] = f2h(v);
                    } else {
                        resh[((size_t)r * NN + node) * HD + (col - HD)] = f2h(v);
                    }
                }
            }
        }
    }

    // attn epilogue: wave w<2 computes el/er for head w from fp32 acc.
    if (w < 2) {
        float al0 = attn_l[(r * HH + w) * DD + lm];
        float al1 = attn_l[(r * HH + w) * DD + lm + 16];
        float ar0 = attn_r[(r * HH + w) * DD + lm];
        float ar1 = attn_r[(r * HH + w) * DD + lm + 16];
        #pragma unroll
        for (int mt = 0; mt < 4; mt++) {
            #pragma unroll
            for (int p = 0; p < 4; p++) {
                float pl = acc[mt][0][p] * al0 + acc[mt][1][p] * al1;
                float pr = acc[mt][0][p] * ar0 + acc[mt][1][p] * ar1;
                #pragma unroll
                for (int off = 1; off < 16; off <<= 1) {
                    pl += __shfl_xor(pl, off, 64);
                    pr += __shfl_xor(pr, off, 64);
                }
                if (lm == 0) {
                    int node = n0 + mt * 16 + lq * 4 + p;
                    if (node < NN) {
                        el[((size_t)r * NN + node) * HH + w] = pl;
                        er[((size_t)r * NN + node) * HH + w] = pr;
                    }
                }
            }
        }
    }
}

// ---------------------------------------------------------------------------
// A: fused partition: per-chunk LDS histogram -> one global atomicAdd per
// touched bucket reserves a range -> scatter into CAP-strided slots.
// ---------------------------------------------------------------------------
__global__ __launch_bounds__(256) void part_kernel(
    const int* __restrict__ src, const int* __restrict__ dst,
    int* __restrict__ bcnt, unsigned* __restrict__ bucketRec)
{
    __shared__ int hh[NB];
    int r = blockIdx.x >> 6;
    int blk = blockIdx.x & 63;
    int tid = threadIdx.x;
    for (int i = tid; i < NB; i += 256) hh[i] = 0;
    __syncthreads();
    const int* S = src + (size_t)r * EE + blk * CHUNK;
    const int* D = dst + (size_t)r * EE + blk * CHUNK;
    for (int i = tid; i < CHUNK; i += 256)
        atomicAdd(&hh[D[i] >> 6], 1);
    __syncthreads();
    for (int i = tid; i < NB; i += 256) {
        int c = hh[i];
        hh[i] = c ? atomicAdd(&bcnt[r * NB + i], c) : 0;
    }
    __syncthreads();
    unsigned* BR = bucketRec + (size_t)r * NBCAP;
    for (int i = tid; i < CHUNK; i += 256) {
        int s = S[i], d = D[i];
        int b = d >> 6;
        int pos = atomicAdd(&hh[b], 1);
        if (pos < CAP)
            BR[((size_t)b << 11) + pos] = (unsigned)s | ((unsigned)(d & 63) << 15);
    }
}

// ---------------------------------------------------------------------------
// B: per-bucket LDS counting sort + exact per-dst softmax -> csrE records.
// v4: staged logits packed half2 (sL 16KB->8KB): LDS 27.8->19.1KB per block
// -> 8 blocks/CU (was 5), 32 waves/CU. fp16-rounded logits used
// consistently for max/sum/weights (consistent softmax, error << tol).
// ---------------------------------------------------------------------------
__global__ __launch_bounds__(256) void bsort_alpha_kernel(
    const unsigned* __restrict__ bucketRec, const int* __restrict__ bcnt,
    const float* __restrict__ el, const float* __restrict__ er,
    uint2* __restrict__ csrE, int* __restrict__ rowp)
{
    __shared__ int cnt64s[4][64];
    __shared__ int segS[65];
    __shared__ int cur[64];
    __shared__ float2 erL[64];
    __shared__ float2 mx2[64];
    __shared__ float2 inv2[64];
    __shared__ unsigned sSD[CAP];
    __shared__ unsigned sL[CAP];      // packed half2(l0,l1)

    int bk = blockIdx.x;            // r*NB + bkt
    int r = bk / NB;
    int bkt = bk - r * NB;
    int tid = threadIdx.x;
    int wv = tid >> 6;
    int cnt = bcnt[bk];
    if (cnt > CAP) cnt = CAP;

    if (tid < 64) {
        cnt64s[0][tid] = 0; cnt64s[1][tid] = 0;
        cnt64s[2][tid] = 0; cnt64s[3][tid] = 0;
        int gn = bkt * 64 + tid;
        erL[tid] = (gn < NN) ? ((const float2*)er)[(size_t)r * NN + gn]
                             : make_float2(0.f, 0.f);
    }
    __syncthreads();
    const unsigned* BR = bucketRec + (size_t)bk * CAP;
    for (int i = tid; i < cnt; i += 256)
        atomicAdd(&cnt64s[wv][(BR[i] >> 15) & 63], 1);
    __syncthreads();
    if (tid < 64) {
        int v = cnt64s[0][tid] + cnt64s[1][tid] + cnt64s[2][tid] + cnt64s[3][tid];
        int x = v;
        #pragma unroll
        for (int off = 1; off < 64; off <<= 1) {
            int tt = __shfl_up(x, off, 64);
            if (tid >= off) x += tt;
        }
        segS[tid] = x - v;
        cur[tid] = x - v;
        if (tid == 63) segS[64] = x;
    }
    __syncthreads();
    const float2* el2 = (const float2*)el + (size_t)r * NN;
    for (int i = tid; i < cnt; i += 256) {
        unsigned rec = BR[i];
        int s = rec & 0x7FFF;
        int d = (rec >> 15) & 63;
        float2 a = el2[s];
        float2 b = erL[d];
        float l0 = a.x + b.x; l0 = l0 > 0.f ? l0 : NEG * l0;
        float l1 = a.y + b.y; l1 = l1 > 0.f ? l1 : NEG * l1;
        int pos = atomicAdd(&cur[d], 1);
        sSD[pos] = rec;
        sL[pos] = (unsigned)f2h(l0) | ((unsigned)f2h(l1) << 16);
    }
    __syncthreads();
    // wave-parallel per-dst softmax: 4 threads per dst, shfl_xor(1,2) reduce
    {
        int d = tid >> 2, sub = tid & 3;
        int b0 = segS[d], e0 = segS[d + 1];
        float m0 = -1e30f, m1 = -1e30f;
        for (int i = b0 + sub; i < e0; i += 4) {
            float2 l = up2(sL[i]);
            m0 = fmaxf(m0, l.x); m1 = fmaxf(m1, l.y);
        }
        m0 = fmaxf(m0, __shfl_xor(m0, 1, 64));
        m0 = fmaxf(m0, __shfl_xor(m0, 2, 64));
        m1 = fmaxf(m1, __shfl_xor(m1, 1, 64));
        m1 = fmaxf(m1, __shfl_xor(m1, 2, 64));
        float s0 = 0.f, s1 = 0.f;
        for (int i = b0 + sub; i < e0; i += 4) {
            float2 l = up2(sL[i]);
            s0 += __expf(l.x - m0); s1 += __expf(l.y - m1);
        }
        s0 += __shfl_xor(s0, 1, 64); s0 += __shfl_xor(s0, 2, 64);
        s1 += __shfl_xor(s1, 1, 64); s1 += __shfl_xor(s1, 2, 64);
        if (sub == 0) {
            mx2[d] = make_float2(m0, m1);
            inv2[d] = make_float2(1.f / fmaxf(s0, 1e-9f), 1.f / fmaxf(s1, 1e-9f));
            int gn = bkt * 64 + d;
            if (gn < NN) {
                int len = e0 - b0;
                rowp[r * RPS + gn] = (int)(((unsigned)(bkt * CAP + b0)) | ((unsigned)len << 20));
            }
        }
    }
    __syncthreads();
    uint2* E = csrE + (size_t)bk * CAP;
    for (int i = tid; i < cnt; i += 256) {
        unsigned rec = sSD[i];
        int d = (rec >> 15) & 63;
        float2 l = up2(sL[i]);
        float w0 = __expf(l.x - mx2[d].x) * inv2[d].x;
        float w1 = __expf(l.y - mx2[d].y) * inv2[d].y;
        E[i] = make_uint2(rec, (unsigned)f2h(w0) | ((unsigned)f2h(w1) << 16));
    }
}

// ---------------------------------------------------------------------------
// K6 v6: diffusion hop, PULL wide-gather, 8 dsts/wave, 8 feats/lane, dual
// stream per dst + 2-stage register pipeline (rec j+2, feat j+1).
// v6: per-lane DIVERGENT trip count (j < own cl, not wave-max) -- lanes past
// their segment are exec-masked and issue NO gathers. With degree ~Po(16),
// max-of-8 ~= 26 vs mean 16: cuts ~35% of all feature-gather requests.
// ---------------------------------------------------------------------------
__global__ __launch_bounds__(256) void hop_kernel(
    const ushort* __restrict__ tin, ushort* __restrict__ tout,
    const uint2* __restrict__ csrE, const int* __restrict__ rowp)
{
    int nbk = gridDim.x;
    int q = nbk >> 3, rmd = nbk & 7;
    int xcd = blockIdx.x & 7, pos = blockIdx.x >> 3;
    int bid = (xcd < rmd ? xcd * (q + 1) : rmd * (q + 1) + (xcd - rmd) * q) + pos;

    int w = (bid * 256 + (int)threadIdx.x) >> 6;
    if (w >= RR * (NN / 8)) return;
    int lane = threadIdx.x & 63;
    int g = lane >> 3;                 // dst group 0..7
    int f = (lane & 7) * 8;            // feature base 0..56
    int sh = ((lane >> 2) & 1) * 16;   // head select: f>=32 <=> bit2 of lane
    int r = w / (NN / 8);
    int n0 = (w - r * (NN / 8)) * 8;

    unsigned pv = (unsigned)rowp[r * RPS + n0 + g];
    int bg = (int)(pv & 0xFFFFF);
    int len = (int)(pv >> 20);
    int eg = bg + len;
    int cl = (len + 1) >> 1;           // stream A length (ceil half)
    int b2 = bg + cl;                  // stream B start

    int lastA = bg + cl - 1;
    lastA = lastA > bg ? lastA : bg;
    int lastB = eg - 1;
    lastB = lastB > b2 ? lastB : b2;

    const ushort* T = tin + (size_t)r * NN * HD;
    const uint2* E = csrE + (size_t)r * NBCAP;

    // pipeline prologue: recs for j=0, j=1; features for j=0
    int iA1 = bg + 1 < lastA ? bg + 1 : lastA;
    int iB1 = b2 + 1 < lastB ? b2 + 1 : lastB;
    uint2 raC = E[lastA < bg ? lastA : bg], rbC = E[b2 < lastB ? b2 : lastB];
    uint2 raN = E[iA1], rbN = E[iB1];
    int na0 = (int)(raC.x & 0x7FFF); na0 = na0 < NN ? na0 : 0;
    int nb0 = (int)(rbC.x & 0x7FFF); nb0 = nb0 < NN ? nb0 : 0;
    hf8 fa = *(const hf8*)&T[(size_t)na0 * HD + f];
    hf8 fb = *(const hf8*)&T[(size_t)nb0 * HD + f];

    float accA[8] = {0.f, 0.f, 0.f, 0.f, 0.f, 0.f, 0.f, 0.f};
    float accB[8] = {0.f, 0.f, 0.f, 0.f, 0.f, 0.f, 0.f, 0.f};
    #pragma unroll 2
    for (int j = 0; j < cl; j++) {     // per-lane bound: masked lanes issue 0 VMEM
        // issue rec loads for j+2
        int ja = bg + j + 2; ja = ja < lastA ? ja : lastA;
        int jb = b2 + j + 2; jb = jb < lastB ? jb : lastB;
        uint2 ra2 = E[ja];
        uint2 rb2 = E[jb];
        // issue feature loads for j+1 (addresses from raN/rbN)
        int na1 = (int)(raN.x & 0x7FFF); na1 = na1 < NN ? na1 : 0;
        int nb1 = (int)(rbN.x & 0x7FFF); nb1 = nb1 < NN ? nb1 : 0;
        hf8 fa1 = *(const hf8*)&T[(size_t)na1 * HD + f];
        hf8 fb1 = *(const hf8*)&T[(size_t)nb1 * HD + f];
        // consume current (j < cl guaranteed for stream A)
        float wa = h2f((ushort)(raC.y >> sh));
        float wb = (b2 + j < eg) ? h2f((ushort)(rbC.y >> sh)) : 0.f;
        #pragma unroll
        for (int k2 = 0; k2 < 8; k2++) {
            accA[k2] += wa * (float)fa[k2];
            accB[k2] += wb * (float)fb[k2];
        }
        // rotate
        raC = raN; raN = ra2;
        rbC = rbN; rbN = rb2;
        fa = fa1; fb = fb1;
    }
    ushort o[8];
    #pragma unroll
    for (int k = 0; k < 8; k++) o[k] = f2h(accA[k] + accB[k]);
    *(uint4*)&tout[((size_t)r * NN + n0 + g) * HD + f] = *(uint4*)o;
}

// ---------------------------------------------------------------------------
// K7 v2: final — 4 lanes per (node, head), 8 feats/lane; partial dots
// reduced via shfl_xor(1,2); head-mean via shfl_down(4).
// ---------------------------------------------------------------------------
__global__ __launch_bounds__(256) void final_kernel(
    const ushort* __restrict__ t0, const ushort* __restrict__ t1,
    const ushort* __restrict__ t2, const ushort* __restrict__ t3,
    const ushort* __restrict__ resh,
    const float* __restrict__ hal, const float* __restrict__ har,
    const float* __restrict__ w_rel, const float* __restrict__ b_rel,
    float* __restrict__ out)
{
    int idx = blockIdx.x * 256 + threadIdx.x;   // over NN*HH*4 = 160000
    if (idx >= NN * HH * 4) return;
    int fq = idx & 3;                 // feature quarter: feats [fq*8, fq*8+8)
    int h_ = (idx >> 2) & 1;
    int n = idx >> 3;
    const ushort* tb[4] = {t0, t1, t2, t3};
    float o[8];
    #pragma unroll
    for (int d = 0; d < 8; d++) o[d] = 0.f;

    for (int r = 0; r < RR; r++) {
        float wr = b_rel[r];
        #pragma unroll
        for (int j = 0; j < RR; j++) wr += w_rel[r * RR + j];
        const float* hp = hal + (r * HH + h_) * DD + fq * 8;
        const float* gp = har + (r * HH + h_) * DD + fq * 8;
        float4 ha0 = *(const float4*)hp;
        float4 ha1 = *(const float4*)(hp + 4);
        float4 hr0 = *(const float4*)gp;
        float4 hr1 = *(const float4*)(gp + 4);
        float halc[8] = {ha0.x, ha0.y, ha0.z, ha0.w, ha1.x, ha1.y, ha1.z, ha1.w};
        float harc[8] = {hr0.x, hr0.y, hr0.z, hr0.w, hr1.x, hr1.y, hr1.z, hr1.w};

        size_t tbase = ((size_t)r * NN + n) * HD + h_ * DD + fq * 8;
        uint4 tv[4];
        float sq[4], dl[4], dr = 0.f;
        #pragma unroll
        for (int k = 0; k < 4; k++) {
            tv[k] = *(const uint4*)(tb[k] + tbase);
            unsigned ww[4] = {tv[k].x, tv[k].y, tv[k].z, tv[k].w};
            float s = 0.f, d1 = 0.f;
            #pragma unroll
            for (int j = 0; j < 4; j++) {
                float2 v = up2(ww[j]);
                s  += v.x * v.x + v.y * v.y;
                d1 += v.x * halc[2 * j] + v.y * halc[2 * j + 1];
                if (k == 0)
                    dr += v.x * harc[2 * j] + v.y * harc[2 * j + 1];
            }
            sq[k] = s; dl[k] = d1;
        }
        #pragma unroll
        for (int k = 0; k < 4; k++) {
            sq[k] += __shfl_xor(sq[k], 1, 64); sq[k] += __shfl_xor(sq[k], 2, 64);
            dl[k] += __shfl_xor(dl[k], 1, 64); dl[k] += __shfl_xor(dl[k], 2, 64);
        }
        dr += __shfl_xor(dr, 1, 64); dr += __shfl_xor(dr, 2, 64);

        float inv[4], lg[4], mx = -1e30f;
        #pragma unroll
        for (int k = 0; k < 4; k++)
            inv[k] = 1.f / fmaxf(sqrtf(sq[k]), 1e-9f);
        #pragma unroll
        for (int k = 0; k < 4; k++) {
            float l = dl[k] * inv[k] + dr * inv[0];
            l = l > 0.f ? l : NEG * l;
            lg[k] = l;
            mx = fmaxf(mx, l);
        }
        float ssum = 0.f;
        #pragma unroll
        for (int k = 0; k < 4; k++) { lg[k] = __expf(lg[k] - mx); ssum += lg[k]; }
        float sw = wr / ssum;
        #pragma unroll
        for (int k = 0; k < 4; k++) {
            float coef = lg[k] * inv[k] * sw;
            unsigned ww[4] = {tv[k].x, tv[k].y, tv[k].z, tv[k].w};
            #pragma unroll
            for (int j = 0; j < 4; j++) {
                float2 v = up2(ww[j]);
                o[2 * j]     += coef * v.x;
                o[2 * j + 1] += coef * v.y;
            }
        }
        uint4 rv = *(const uint4*)(resh + tbase);
        unsigned rw[4] = {rv.x, rv.y, rv.z, rv.w};
        #pragma unroll
        for (int j = 0; j < 4; j++) {
            float2 v = up2(rw[j]);
            o[2 * j]     += wr * v.x;
            o[2 * j + 1] += wr * v.y;
        }
    }
    // head-mean: h=0 lane pulls h=1 lane (4 apart) and writes out.
    float p[8];
    #pragma unroll
    for (int j = 0; j < 8; j++) p[j] = __shfl_down(o[j], 4, 64);
    if (h_ == 0) {
        float4* op = (float4*)(out + (size_t)n * DD + fq * 8);
        op[0] = make_float4(0.5f * (o[0] + p[0]), 0.5f * (o[1] + p[1]),
                            0.5f * (o[2] + p[2]), 0.5f * (o[3] + p[3]));
        op[1] = make_float4(0.5f * (o[4] + p[4]), 0.5f * (o[5] + p[5]),
                            0.5f * (o[6] + p[6]), 0.5f * (o[7] + p[7]));
    }
}

// ---------------------------------------------------------------------------
extern "C" void kernel_launch(void* const* d_in, const int* in_sizes, int n_in,
                              void* d_out, int out_size, void* d_ws, size_t ws_size,
                              hipStream_t stream) {
    (void)in_sizes; (void)n_in; (void)out_size; (void)ws_size;
    const float* h     = (const float*)d_in[0];
    const int*   src   = (const int*)d_in[1];
    const int*   dst   = (const int*)d_in[2];
    const float* fcw   = (const float*)d_in[3];
    const float* resw  = (const float*)d_in[4];
    const float* atl   = (const float*)d_in[5];
    const float* atr   = (const float*)d_in[6];
    const float* hal   = (const float*)d_in[7];
    const float* har   = (const float*)d_in[8];
    const float* wrel  = (const float*)d_in[9];
    const float* brel  = (const float*)d_in[10];
    float* out = (float*)d_out;

    float* ws = (float*)d_ws;
    size_t off = 0;
    float* el   = ws + off;  off += (size_t)RR * NN * HH;
    float* er   = ws + off;  off += (size_t)RR * NN * HH;
    uint2* csrE = (uint2*)(ws + off);      off += (size_t)RR * NBCAP * 2;
    unsigned* bucketRec = (unsigned*)(ws + off); off += (size_t)RR * NBCAP;
    ushort* resh = (ushort*)(ws + off);    off += (size_t)RR * NN * HD / 2;
    ushort* t0  = (ushort*)(ws + off);     off += (size_t)RR * NN * HD / 2;
    ushort* t1  = (ushort*)(ws + off);     off += (size_t)RR * NN * HD / 2;
    ushort* t2  = (ushort*)(ws + off);     off += (size_t)RR * NN * HD / 2;
    ushort* t3  = (ushort*)(ws + off);     off += (size_t)RR * NN * HD / 2;
    ushort* wb  = (ushort*)(ws + off);     off += (size_t)RR * 128 * IN / 2;
    ushort* hb  = (ushort*)(ws + off);     off += (size_t)NN * IN / 2;
    int* rowp   = (int*)(ws + off);  off += (size_t)RR * RPS;
    int* bcnt   = (int*)(ws + off);  off += (size_t)RR * NB;

    cvt_kernel<<<(RR * 128 * IN + HTOT + 255) / 256, 256, 0, stream>>>(h, fcw, resw, wb, hb, bcnt);
    proj_mfma<<<313 * RR, 256, 0, stream>>>(hb, wb, atl, atr, t0, resh, el, er);
    part_kernel<<<RR * NBLK, 256, 0, stream>>>(src, dst, bcnt, bucketRec);
    bsort_alpha_kernel<<<RR * NB, 256, 0, stream>>>(bucketRec, bcnt, el, er, csrE, rowp);
    hop_kernel<<<(RR * (NN / 8) + 3) / 4, 256, 0, stream>>>(t0, t1, csrE, rowp);
    hop_kernel<<<(RR * (NN / 8) + 3) / 4, 256, 0, stream>>>(t1, t2, csrE, rowp);
    hop_kernel<<<(RR * (NN / 8) + 3) / 4, 256, 0, stream>>>(t2, t3, csrE, rowp);
    final_kernel<<<(NN * HH * 4 + 255) / 256, 256, 0, stream>>>(t0, t1, t2, t3, resh, hal, har, wrel, brel, out);
}

// Round 6
// 214.203 us; speedup vs baseline: 1.3555x; 1.1019x over previous
//
#include <hip/hip_runtime.h>
#include <hip/hip_bf16.h>

#define NN 20000
#define IN 128
#define HH 2
#define DD 32
#define HD 64
#define KK 3
#define RR 5
#define EE 320000
#define NEG 0.2f

#define PADK 136
#define NB 313     // buckets per relation (64 dsts each)
#define NBLK 64    // partition blocks per relation
#define CHUNK 5000 // EE / NBLK
#define CAP 2048   // slots per bucket (mean 1024, sd ~32); stride = 2^11
#define NBCAP (NB * CAP)
#define RPS 20004  // rowp row stride
#define HTOT (NN * IN / 4)   // float4 chunks of h
#define PARTB (RR * NBLK)    // 320 part blocks prefixed to proj launch

typedef short v8s __attribute__((ext_vector_type(8)));
typedef float v4f __attribute__((ext_vector_type(4)));
typedef _Float16 hf8 __attribute__((ext_vector_type(8)));

__device__ __forceinline__ ushort f2b(float f) {
    unsigned u = __float_as_uint(f);
    unsigned r = (u + 0x7fff + ((u >> 16) & 1)) >> 16;   // RNE
    return (ushort)r;
}
__device__ __forceinline__ ushort f2h(float f) {
    _Float16 h = (_Float16)f;
    return __builtin_bit_cast(ushort, h);
}
__device__ __forceinline__ float h2f(ushort u) {
    _Float16 h = __builtin_bit_cast(_Float16, u);
    return (float)h;
}
__device__ __forceinline__ float2 up2(unsigned u) {
    return make_float2(h2f((ushort)(u & 0xFFFF)), h2f((ushort)(u >> 16)));
}

// ---------------------------------------------------------------------------
// K0: weights -> wb bf16 (transposed+fused), h -> hb bf16, bcnt zeroing.
// ---------------------------------------------------------------------------
__global__ __launch_bounds__(256) void cvt_kernel(
    const float* __restrict__ h, const float* __restrict__ fcw,
    const float* __restrict__ resw, ushort* __restrict__ wb,
    ushort* __restrict__ hb, int* __restrict__ bcnt)
{
    int j = blockIdx.x * 256 + threadIdx.x;
    if (j < RR * NB) bcnt[j] = 0;
    if (j < RR * 128 * IN) {
        int k = j & 127;
        int c = (j >> 7) & 127;
        int r = j >> 14;
        float v = (c < HD) ? fcw[(r * IN + k) * HD + c] : resw[(r * IN + k) * HD + (c - HD)];
        wb[j] = f2b(v);
    }
    int t = j - RR * 128 * IN;
    if (t >= 0 && t < HTOT) {
        float4 v = ((const float4*)h)[t];
        ((ushort4*)hb)[t] = make_ushort4(f2b(v.x), f2b(v.y), f2b(v.z), f2b(v.w));
    }
}

// ---------------------------------------------------------------------------
// K1: MERGED proj + partition. Blocks [0,PARTB): edge partition (independent
// of proj, complementary pipes -> runs concurrently, hidden under proj).
// Blocks [PARTB,..): bf16-MFMA projection + fused attn epilogue.
// LDS aliased (part's hist lives in proj's As) so footprint stays 52KB.
// ---------------------------------------------------------------------------
__global__ __launch_bounds__(256) void projpart_kernel(
    const ushort* __restrict__ hb, const ushort* __restrict__ wb,
    const float* __restrict__ attn_l, const float* __restrict__ attn_r,
    ushort* __restrict__ t0, ushort* __restrict__ resh,
    float* __restrict__ el, float* __restrict__ er,
    const int* __restrict__ src, const int* __restrict__ dst,
    int* __restrict__ bcnt, unsigned* __restrict__ bucketRec)
{
    __shared__ ushort As[64 * PADK];
    __shared__ ushort Bs[128 * PADK];
    int tid = threadIdx.x;

    if (blockIdx.x < PARTB) {
        // ---- partition path ----
        int* hh = (int*)As;   // alias: disjoint code path, same block
        int r = blockIdx.x >> 6;
        int blk = blockIdx.x & 63;
        for (int i = tid; i < NB; i += 256) hh[i] = 0;
        __syncthreads();
        const int* S = src + (size_t)r * EE + blk * CHUNK;
        const int* D = dst + (size_t)r * EE + blk * CHUNK;
        for (int i = tid; i < CHUNK; i += 256)
            atomicAdd(&hh[D[i] >> 6], 1);
        __syncthreads();
        for (int i = tid; i < NB; i += 256) {
            int c = hh[i];
            hh[i] = c ? atomicAdd(&bcnt[r * NB + i], c) : 0;
        }
        __syncthreads();
        unsigned* BR = bucketRec + (size_t)r * NBCAP;
        for (int i = tid; i < CHUNK; i += 256) {
            int s = S[i], d = D[i];
            int b = d >> 6;
            int pos = atomicAdd(&hh[b], 1);
            if (pos < CAP)
                BR[((size_t)b << 11) + pos] = (unsigned)s | ((unsigned)(d & 63) << 15);
        }
        return;
    }

    // ---- projection path ----
    int bx = blockIdx.x - PARTB;
    int r = bx / 313;
    int tile = bx - r * 313;
    int n0 = tile * 64;

    #pragma unroll
    for (int i = 0; i < 4; i++) {
        int c = tid + 256 * i;
        int row = c >> 4;            // 16 uint4 per row
        int off = (c & 15) * 8;
        int gn = n0 + row;
        uint4 v = make_uint4(0u, 0u, 0u, 0u);
        if (gn < NN) v = *(const uint4*)&hb[(size_t)gn * IN + off];
        *(uint4*)&As[row * PADK + off] = v;
    }
    const ushort* wr = wb + (size_t)r * 128 * IN;
    #pragma unroll
    for (int i = 0; i < 8; i++) {
        int c = tid + 256 * i;
        int row = c >> 4;
        int off = (c & 15) * 8;
        *(uint4*)&Bs[row * PADK + off] = *(const uint4*)&wr[row * IN + off];
    }
    __syncthreads();

    int w = tid >> 6, lane = tid & 63;
    int lm = lane & 15, lq = lane >> 4;

    v4f acc[4][2];
    #pragma unroll
    for (int mt = 0; mt < 4; mt++)
        #pragma unroll
        for (int nt = 0; nt < 2; nt++) acc[mt][nt] = (v4f){0.f, 0.f, 0.f, 0.f};

    const ushort* Ab = &As[lm * PADK + lq * 8];
    const ushort* Bb = &Bs[(w * 32 + lm) * PADK + lq * 8];

    #pragma unroll
    for (int ks = 0; ks < 4; ks++) {
        v8s a[4], b[2];
        #pragma unroll
        for (int mt = 0; mt < 4; mt++) a[mt] = *(const v8s*)(Ab + mt * 16 * PADK + ks * 32);
        #pragma unroll
        for (int nt = 0; nt < 2; nt++) b[nt] = *(const v8s*)(Bb + nt * 16 * PADK + ks * 32);
        #pragma unroll
        for (int mt = 0; mt < 4; mt++)
            #pragma unroll
            for (int nt = 0; nt < 2; nt++)
                acc[mt][nt] = __builtin_amdgcn_mfma_f32_16x16x32_bf16(a[mt], b[nt], acc[mt][nt], 0, 0, 0);
    }

    int colbase = w * 32 + lm;
    #pragma unroll
    for (int mt = 0; mt < 4; mt++) {
        #pragma unroll
        for (int nt = 0; nt < 2; nt++) {
            int col = colbase + nt * 16;
            #pragma unroll
            for (int p = 0; p < 4; p++) {
                int node = n0 + mt * 16 + lq * 4 + p;
                if (node < NN) {
                    float v = acc[mt][nt][p];
                    if (col < HD) {
                        t0[((size_t)r * NN + node) * HD + col] = f2h(v);
                    } else {
                        resh[((size_t)r * NN + node) * HD + (col - HD)] = f2h(v);
                    }
                }
            }
        }
    }

    if (w < 2) {
        float al0 = attn_l[(r * HH + w) * DD + lm];
        float al1 = attn_l[(r * HH + w) * DD + lm + 16];
        float ar0 = attn_r[(r * HH + w) * DD + lm];
        float ar1 = attn_r[(r * HH + w) * DD + lm + 16];
        #pragma unroll
        for (int mt = 0; mt < 4; mt++) {
            #pragma unroll
            for (int p = 0; p < 4; p++) {
                float pl = acc[mt][0][p] * al0 + acc[mt][1][p] * al1;
                float pr = acc[mt][0][p] * ar0 + acc[mt][1][p] * ar1;
                #pragma unroll
                for (int off = 1; off < 16; off <<= 1) {
                    pl += __shfl_xor(pl, off, 64);
                    pr += __shfl_xor(pr, off, 64);
                }
                if (lm == 0) {
                    int node = n0 + mt * 16 + lq * 4 + p;
                    if (node < NN) {
                        el[((size_t)r * NN + node) * HH + w] = pl;
                        er[((size_t)r * NN + node) * HH + w] = pr;
                    }
                }
            }
        }
    }
}

// ---------------------------------------------------------------------------
// B: bsort + softmax + FUSED HOP1. After the softmax, edge records AND
// weights are already in LDS -> hop1 computed in-place (8-lane groups gather
// t0 rows; recs/weights broadcast from LDS; zero record traffic).
// csrE written with EVEN-ALIGNED per-dst segments (pad slot = {0,0} so
// hops 2/3 can load records as aligned uint4 pairs); rowp = paddedBegin|len<<20.
// ---------------------------------------------------------------------------
__global__ __launch_bounds__(256) void bsort_alpha_hop1_kernel(
    const unsigned* __restrict__ bucketRec, const int* __restrict__ bcnt,
    const float* __restrict__ el, const float* __restrict__ er,
    const ushort* __restrict__ t0, uint2* __restrict__ csrE,
    int* __restrict__ rowp, ushort* __restrict__ t1)
{
    __shared__ int cnt64s[4][64];
    __shared__ int segS[65];
    __shared__ int cur[64];
    __shared__ int pbS[64];
    __shared__ float2 erL[64];
    __shared__ float2 mx2[64];
    __shared__ float2 inv2[64];
    __shared__ unsigned sSD[CAP];
    __shared__ unsigned sL[CAP];      // logits (packed half2) then weights

    int bk = blockIdx.x;            // r*NB + bkt
    int r = bk / NB;
    int bkt = bk - r * NB;
    int tid = threadIdx.x;
    int wv = tid >> 6;
    int cnt = bcnt[bk];
    if (cnt > CAP - 64) cnt = CAP - 64;   // headroom for per-dst pad slots

    if (tid < 64) {
        cnt64s[0][tid] = 0; cnt64s[1][tid] = 0;
        cnt64s[2][tid] = 0; cnt64s[3][tid] = 0;
        int gn = bkt * 64 + tid;
        erL[tid] = (gn < NN) ? ((const float2*)er)[(size_t)r * NN + gn]
                             : make_float2(0.f, 0.f);
    }
    __syncthreads();
    const unsigned* BR = bucketRec + (size_t)bk * CAP;
    for (int i = tid; i < cnt; i += 256)
        atomicAdd(&cnt64s[wv][(BR[i] >> 15) & 63], 1);
    __syncthreads();
    if (tid < 64) {
        int v = cnt64s[0][tid] + cnt64s[1][tid] + cnt64s[2][tid] + cnt64s[3][tid];
        int x = v;
        int y = v & 1;
        #pragma unroll
        for (int off = 1; off < 64; off <<= 1) {
            int tx = __shfl_up(x, off, 64);
            int ty = __shfl_up(y, off, 64);
            if (tid >= off) { x += tx; y += ty; }
        }
        segS[tid] = x - v;
        cur[tid]  = x - v;
        pbS[tid]  = (x - v) + (y - (v & 1));   // even-aligned padded begin
        if (tid == 63) segS[64] = x;
    }
    __syncthreads();
    const float2* el2 = (const float2*)el + (size_t)r * NN;
    for (int i = tid; i < cnt; i += 256) {
        unsigned rec = BR[i];
        int s = rec & 0x7FFF;
        int d = (rec >> 15) & 63;
        float2 a = el2[s];
        float2 b = erL[d];
        float l0 = a.x + b.x; l0 = l0 > 0.f ? l0 : NEG * l0;
        float l1 = a.y + b.y; l1 = l1 > 0.f ? l1 : NEG * l1;
        int pos = atomicAdd(&cur[d], 1);
        sSD[pos] = rec;
        sL[pos] = (unsigned)f2h(l0) | ((unsigned)f2h(l1) << 16);
    }
    __syncthreads();
    // wave-parallel per-dst softmax: 4 threads per dst, shfl_xor(1,2) reduce
    {
        int d = tid >> 2, sub = tid & 3;
        int b0 = segS[d], e0 = segS[d + 1];
        float m0 = -1e30f, m1 = -1e30f;
        for (int i = b0 + sub; i < e0; i += 4) {
            float2 l = up2(sL[i]);
            m0 = fmaxf(m0, l.x); m1 = fmaxf(m1, l.y);
        }
        m0 = fmaxf(m0, __shfl_xor(m0, 1, 64));
        m0 = fmaxf(m0, __shfl_xor(m0, 2, 64));
        m1 = fmaxf(m1, __shfl_xor(m1, 1, 64));
        m1 = fmaxf(m1, __shfl_xor(m1, 2, 64));
        float s0 = 0.f, s1 = 0.f;
        for (int i = b0 + sub; i < e0; i += 4) {
            float2 l = up2(sL[i]);
            s0 += __expf(l.x - m0); s1 += __expf(l.y - m1);
        }
        s0 += __shfl_xor(s0, 1, 64); s0 += __shfl_xor(s0, 2, 64);
        s1 += __shfl_xor(s1, 1, 64); s1 += __shfl_xor(s1, 2, 64);
        if (sub == 0) {
            mx2[d] = make_float2(m0, m1);
            inv2[d] = make_float2(1.f / fmaxf(s0, 1e-9f), 1.f / fmaxf(s1, 1e-9f));
            int gn = bkt * 64 + d;
            if (gn < NN) {
                int len = e0 - b0;
                rowp[r * RPS + gn] =
                    (int)(((unsigned)(bkt * CAP + pbS[d])) | ((unsigned)len << 20));
            }
        }
    }
    __syncthreads();
    uint2* E = csrE + (size_t)bk * CAP;
    for (int i = tid; i < cnt; i += 256) {
        unsigned rec = sSD[i];
        int d = (rec >> 15) & 63;
        float2 l = up2(sL[i]);
        float w0 = __expf(l.x - mx2[d].x) * inv2[d].x;
        float w1 = __expf(l.y - mx2[d].y) * inv2[d].y;
        unsigned wp = (unsigned)f2h(w0) | ((unsigned)f2h(w1) << 16);
        E[pbS[d] + (i - segS[d])] = make_uint2(rec, wp);
        sL[i] = wp;                       // repack: weights for hop1 phase
    }
    if (tid < 64) {
        int len = segS[tid + 1] - segS[tid];
        if (len & 1) E[pbS[tid] + len] = make_uint2(0u, 0u);   // pad slot
    }
    __syncthreads();

    // ---- fused hop1: 8-lane groups, recs/weights broadcast from LDS ----
    int lane = tid & 63;
    int g = lane >> 3;
    int f = (lane & 7) * 8;
    int sh = ((lane >> 2) & 1) * 16;
    const ushort* T0 = t0 + (size_t)r * NN * HD;
    #pragma unroll
    for (int half = 0; half < 2; half++) {
        int d = half * 32 + wv * 8 + g;
        int b0 = segS[d];
        int len = segS[d + 1] - b0;
        float acc[8] = {0.f, 0.f, 0.f, 0.f, 0.f, 0.f, 0.f, 0.f};
        if (len > 0) {
            float wC = h2f((ushort)(sL[b0] >> sh));
            int sC = sSD[b0] & 0x7FFF;
            hf8 fC = *(const hf8*)&T0[(size_t)sC * HD + f];
            for (int j = 0; j < len; j++) {
                int jn = j + 1 < len ? j + 1 : len - 1;
                float wN = h2f((ushort)(sL[b0 + jn] >> sh));
                int sN = sSD[b0 + jn] & 0x7FFF;
                hf8 fN = *(const hf8*)&T0[(size_t)sN * HD + f];
                #pragma unroll
                for (int k = 0; k < 8; k++) acc[k] += wC * (float)fC[k];
                wC = wN; fC = fN;
            }
        }
        int node = bkt * 64 + d;
        if (node < NN) {
            ushort o[8];
            #pragma unroll
            for (int k = 0; k < 8; k++) o[k] = f2h(acc[k]);
            *(uint4*)&t1[((size_t)r * NN + node) * HD + f] = *(uint4*)o;
        }
    }
}

// ---------------------------------------------------------------------------
// K6 v7 (hops 2,3): paired-record single stream. Segments even-aligned in
// csrE -> records load as aligned uint4 (2 edges per VMEM). Pad slot has
// w=0 so odd tails need no special case. 2-ahead rec / 1-ahead feat pipeline.
// XCD-aware bijective swizzle kept.
// ---------------------------------------------------------------------------
__global__ __launch_bounds__(256) void hop_kernel(
    const ushort* __restrict__ tin, ushort* __restrict__ tout,
    const uint2* __restrict__ csrE, const int* __restrict__ rowp)
{
    int nbk = gridDim.x;
    int q = nbk >> 3, rmd = nbk & 7;
    int xcd = blockIdx.x & 7, pos = blockIdx.x >> 3;
    int bid = (xcd < rmd ? xcd * (q + 1) : rmd * (q + 1) + (xcd - rmd) * q) + pos;

    int w = (bid * 256 + (int)threadIdx.x) >> 6;
    if (w >= RR * (NN / 8)) return;
    int lane = threadIdx.x & 63;
    int g = lane >> 3;                 // dst group 0..7
    int f = (lane & 7) * 8;            // feature base 0..56
    int sh = ((lane >> 2) & 1) * 16;   // head select
    int r = w / (NN / 8);
    int n0 = (w - r * (NN / 8)) * 8;

    unsigned pv = (unsigned)rowp[r * RPS + n0 + g];
    int bg = (int)(pv & 0xFFFFF);      // even
    int len = (int)(pv >> 20);
    int pairs = (len + 1) >> 1;
    int lastP = pairs > 0 ? pairs - 1 : 0;

    const ushort* T = tin + (size_t)r * NN * HD;
    const uint4* E4 = (const uint4*)(csrE + (size_t)r * NBCAP);
    int base4 = bg >> 1;

    // prologue: rec pair 0,1; feats for pair 0
    uint4 rC = E4[base4];
    uint4 rN = E4[base4 + (1 < pairs ? 1 : lastP)];
    int s0 = (int)(rC.x & 0x7FFF); s0 = s0 < NN ? s0 : 0;
    int s1 = (int)(rC.z & 0x7FFF); s1 = s1 < NN ? s1 : 0;
    hf8 f0 = *(const hf8*)&T[(size_t)s0 * HD + f];
    hf8 f1 = *(const hf8*)&T[(size_t)s1 * HD + f];

    float acc[8] = {0.f, 0.f, 0.f, 0.f, 0.f, 0.f, 0.f, 0.f};
    #pragma unroll 2
    for (int j = 0; j < pairs; j++) {    // per-lane bound
        int j2 = j + 2 < pairs ? j + 2 : lastP;
        uint4 r2 = E4[base4 + j2];
        int n0i = (int)(rN.x & 0x7FFF); n0i = n0i < NN ? n0i : 0;
        int n1i = (int)(rN.z & 0x7FFF); n1i = n1i < NN ? n1i : 0;
        hf8 g0 = *(const hf8*)&T[(size_t)n0i * HD + f];
        hf8 g1 = *(const hf8*)&T[(size_t)n1i * HD + f];
        float w0 = h2f((ushort)(rC.y >> sh));
        float w1 = h2f((ushort)(rC.w >> sh));   // pad slot -> 0
        #pragma unroll
        for (int k = 0; k < 8; k++) {
            acc[k] += w0 * (float)f0[k];
            acc[k] += w1 * (float)f1[k];
        }
        rC = rN; rN = r2;
        f0 = g0; f1 = g1;
    }
    ushort o[8];
    #pragma unroll
    for (int k = 0; k < 8; k++) o[k] = f2h(acc[k]);
    *(uint4*)&tout[((size_t)r * NN + n0 + g) * HD + f] = *(uint4*)o;
}

// ---------------------------------------------------------------------------
// K7: final — 4 lanes per (node, head), 8 feats/lane; shfl reductions.
// ---------------------------------------------------------------------------
__global__ __launch_bounds__(256) void final_kernel(
    const ushort* __restrict__ t0, const ushort* __restrict__ t1,
    const ushort* __restrict__ t2, const ushort* __restrict__ t3,
    const ushort* __restrict__ resh,
    const float* __restrict__ hal, const float* __restrict__ har,
    const float* __restrict__ w_rel, const float* __restrict__ b_rel,
    float* __restrict__ out)
{
    int idx = blockIdx.x * 256 + threadIdx.x;   // over NN*HH*4 = 160000
    if (idx >= NN * HH * 4) return;
    int fq = idx & 3;
    int h_ = (idx >> 2) & 1;
    int n = idx >> 3;
    const ushort* tb[4] = {t0, t1, t2, t3};
    float o[8];
    #pragma unroll
    for (int d = 0; d < 8; d++) o[d] = 0.f;

    for (int r = 0; r < RR; r++) {
        float wr = b_rel[r];
        #pragma unroll
        for (int j = 0; j < RR; j++) wr += w_rel[r * RR + j];
        const float* hp = hal + (r * HH + h_) * DD + fq * 8;
        const float* gp = har + (r * HH + h_) * DD + fq * 8;
        float4 ha0 = *(const float4*)hp;
        float4 ha1 = *(const float4*)(hp + 4);
        float4 hr0 = *(const float4*)gp;
        float4 hr1 = *(const float4*)(gp + 4);
        float halc[8] = {ha0.x, ha0.y, ha0.z, ha0.w, ha1.x, ha1.y, ha1.z, ha1.w};
        float harc[8] = {hr0.x, hr0.y, hr0.z, hr0.w, hr1.x, hr1.y, hr1.z, hr1.w};

        size_t tbase = ((size_t)r * NN + n) * HD + h_ * DD + fq * 8;
        uint4 tv[4];
        float sq[4], dl[4], dr = 0.f;
        #pragma unroll
        for (int k = 0; k < 4; k++) {
            tv[k] = *(const uint4*)(tb[k] + tbase);
            unsigned ww[4] = {tv[k].x, tv[k].y, tv[k].z, tv[k].w};
            float s = 0.f, d1 = 0.f;
            #pragma unroll
            for (int j = 0; j < 4; j++) {
                float2 v = up2(ww[j]);
                s  += v.x * v.x + v.y * v.y;
                d1 += v.x * halc[2 * j] + v.y * halc[2 * j + 1];
                if (k == 0)
                    dr += v.x * harc[2 * j] + v.y * harc[2 * j + 1];
            }
            sq[k] = s; dl[k] = d1;
        }
        #pragma unroll
        for (int k = 0; k < 4; k++) {
            sq[k] += __shfl_xor(sq[k], 1, 64); sq[k] += __shfl_xor(sq[k], 2, 64);
            dl[k] += __shfl_xor(dl[k], 1, 64); dl[k] += __shfl_xor(dl[k], 2, 64);
        }
        dr += __shfl_xor(dr, 1, 64); dr += __shfl_xor(dr, 2, 64);

        float inv[4], lg[4], mx = -1e30f;
        #pragma unroll
        for (int k = 0; k < 4; k++)
            inv[k] = 1.f / fmaxf(sqrtf(sq[k]), 1e-9f);
        #pragma unroll
        for (int k = 0; k < 4; k++) {
            float l = dl[k] * inv[k] + dr * inv[0];
            l = l > 0.f ? l : NEG * l;
            lg[k] = l;
            mx = fmaxf(mx, l);
        }
        float ssum = 0.f;
        #pragma unroll
        for (int k = 0; k < 4; k++) { lg[k] = __expf(lg[k] - mx); ssum += lg[k]; }
        float sw = wr / ssum;
        #pragma unroll
        for (int k = 0; k < 4; k++) {
            float coef = lg[k] * inv[k] * sw;
            unsigned ww[4] = {tv[k].x, tv[k].y, tv[k].z, tv[k].w};
            #pragma unroll
            for (int j = 0; j < 4; j++) {
                float2 v = up2(ww[j]);
                o[2 * j]     += coef * v.x;
                o[2 * j + 1] += coef * v.y;
            }
        }
        uint4 rv = *(const uint4*)(resh + tbase);
        unsigned rw[4] = {rv.x, rv.y, rv.z, rv.w};
        #pragma unroll
        for (int j = 0; j < 4; j++) {
            float2 v = up2(rw[j]);
            o[2 * j]     += wr * v.x;
            o[2 * j + 1] += wr * v.y;
        }
    }
    float p[8];
    #pragma unroll
    for (int j = 0; j < 8; j++) p[j] = __shfl_down(o[j], 4, 64);
    if (h_ == 0) {
        float4* op = (float4*)(out + (size_t)n * DD + fq * 8);
        op[0] = make_float4(0.5f * (o[0] + p[0]), 0.5f * (o[1] + p[1]),
                            0.5f * (o[2] + p[2]), 0.5f * (o[3] + p[3]));
        op[1] = make_float4(0.5f * (o[4] + p[4]), 0.5f * (o[5] + p[5]),
                            0.5f * (o[6] + p[6]), 0.5f * (o[7] + p[7]));
    }
}

// ---------------------------------------------------------------------------
extern "C" void kernel_launch(void* const* d_in, const int* in_sizes, int n_in,
                              void* d_out, int out_size, void* d_ws, size_t ws_size,
                              hipStream_t stream) {
    (void)in_sizes; (void)n_in; (void)out_size; (void)ws_size;
    const float* h     = (const float*)d_in[0];
    const int*   src   = (const int*)d_in[1];
    const int*   dst   = (const int*)d_in[2];
    const float* fcw   = (const float*)d_in[3];
    const float* resw  = (const float*)d_in[4];
    const float* atl   = (const float*)d_in[5];
    const float* atr   = (const float*)d_in[6];
    const float* hal   = (const float*)d_in[7];
    const float* har   = (const float*)d_in[8];
    const float* wrel  = (const float*)d_in[9];
    const float* brel  = (const float*)d_in[10];
    float* out = (float*)d_out;

    float* ws = (float*)d_ws;
    size_t off = 0;
    float* el   = ws + off;  off += (size_t)RR * NN * HH;
    float* er   = ws + off;  off += (size_t)RR * NN * HH;
    uint2* csrE = (uint2*)(ws + off);      off += (size_t)RR * NBCAP * 2;
    unsigned* bucketRec = (unsigned*)(ws + off); off += (size_t)RR * NBCAP;
    ushort* resh = (ushort*)(ws + off);    off += (size_t)RR * NN * HD / 2;
    ushort* t0  = (ushort*)(ws + off);     off += (size_t)RR * NN * HD / 2;
    ushort* t1  = (ushort*)(ws + off);     off += (size_t)RR * NN * HD / 2;
    ushort* t2  = (ushort*)(ws + off);     off += (size_t)RR * NN * HD / 2;
    ushort* t3  = (ushort*)(ws + off);     off += (size_t)RR * NN * HD / 2;
    ushort* wb  = (ushort*)(ws + off);     off += (size_t)RR * 128 * IN / 2;
    ushort* hb  = (ushort*)(ws + off);     off += (size_t)NN * IN / 2;
    int* rowp   = (int*)(ws + off);  off += (size_t)RR * RPS;
    int* bcnt   = (int*)(ws + off);  off += (size_t)RR * NB;

    cvt_kernel<<<(RR * 128 * IN + HTOT + 255) / 256, 256, 0, stream>>>(h, fcw, resw, wb, hb, bcnt);
    projpart_kernel<<<PARTB + 313 * RR, 256, 0, stream>>>(hb, wb, atl, atr, t0, resh, el, er,
                                                          src, dst, bcnt, bucketRec);
    bsort_alpha_hop1_kernel<<<RR * NB, 256, 0, stream>>>(bucketRec, bcnt, el, er, t0, csrE, rowp, t1);
    hop_kernel<<<(RR * (NN / 8) + 3) / 4, 256, 0, stream>>>(t1, t2, csrE, rowp);
    hop_kernel<<<(RR * (NN / 8) + 3) / 4, 256, 0, stream>>>(t2, t3, csrE, rowp);
    final_kernel<<<(NN * HH * 4 + 255) / 256, 256, 0, stream>>>(t0, t1, t2, t3, resh, hal, har, wrel, brel, out);
}